// Round 6
// baseline (508.931 us; speedup 1.0000x reference)
//
#include <hip/hip_runtime.h>
#include <hip/hip_bf16.h>
#include <math.h>

// ---------------------------------------------------------------------------
// Round 13 = r11's barrier-free pipelined gemm_bstat + r12's 4-row dwg_t
// (never co-measured). Theory: r12's gemm stalls on the per-tile
// __syncthreads, whose implicit s_waitcnt vmcnt(0) drains the tile's 16KB of
// HBM stores before the As swap (2 blocks/CU -> nothing hides the drain).
// Barrier-free M-loop + named-set A register double-buffering lets stores
// stream and MFMAs cover the next tile's A loads. LDS 73728->49152 B
// (3 blocks/CU).
//
// ws layout (bytes):
//   yt4    @ 0            25,165,824  bf16 [b][p][192]
//   qkva4  @ 25,165,824   75,497,472  bf16 [b][576][p]
//   qkvb4  @ 100,663,296  75,497,472  bf16 [b][576][p]
//   hbuf4  @ 25,165,824  134,217,728  bf16 [b][1024][p]  (aliases dead qkva/qkvb)
//   xa4    @ 176,160,768  50,331,648  fp32 [b][192][p]
//   gt2    @ 226,492,416  33,554,432  bf16 [z][p][512]   (half-batch)
//   wqkvB  @ 260,046,848     221,184
//   wprojB @ 260,268,032      73,728
//   winB   @ 260,341,760     393,216  (1024x192, rows >=1020 zero)
//   woutB  @ 260,734,976     196,608  (192x512, cols >=510 zero)
//   nrm2p  @ 260,931,584      49,152  fp32 [b][384][8]
//   Gpart  @ 260,980,736   2,359,296  fp32 [b][32][8][576]
//   P      @ 263,340,032      73,728  fp32 [b][8][576]
// total 263,413,760 <= 268,435,456. No atomics, no memsets.
// ---------------------------------------------------------------------------

#define HW_ 16384

typedef __attribute__((ext_vector_type(8))) short bf16x8;
typedef __attribute__((ext_vector_type(4))) float f32x4;
typedef __attribute__((ext_vector_type(16))) float f32x16;
typedef __attribute__((ext_vector_type(4))) int i32x4;

union Pack8 { __hip_bfloat16 h[8]; i32x4 v; };

// ---- weight fp32 -> bf16 conversion (with padding) -------------------------
__global__ __launch_bounds__(256) void convert_weights(
    const float* __restrict__ wqkv, const float* __restrict__ wproj,
    const float* __restrict__ win, const float* __restrict__ wout,
    __hip_bfloat16* __restrict__ oq, __hip_bfloat16* __restrict__ op,
    __hip_bfloat16* __restrict__ oi, __hip_bfloat16* __restrict__ oo) {
  const int i = blockIdx.x * 256 + threadIdx.x;
  if (i < 110592) oq[i] = __float2bfloat16(wqkv[i]);            // 576x192
  if (i < 36864)  op[i] = __float2bfloat16(wproj[i]);           // 192x192
  if (i < 196608) {                                             // 1024x192 pad
    int m = i / 192, k = i - m * 192;
    oi[i] = __float2bfloat16(m < 1020 ? win[m * 192 + k] : 0.f);
  }
  if (i < 98304) {                                              // 192x512 pad
    int m = i >> 9, k = i & 511;
    oo[i] = __float2bfloat16(k < 510 ? wout[m * 510 + k] : 0.f);
  }
}

// ---- channel LN -> transposed bf16 output [p][192]; grid (256, batch) ------
__global__ __launch_bounds__(256) void ln_t_kernel(
    const float* __restrict__ x, const float* __restrict__ w,
    const float* __restrict__ bi, __hip_bfloat16* __restrict__ yt) {
  const int b = blockIdx.y;
  x += (size_t)b * 192 * HW_;
  yt += (size_t)b * HW_ * 192;
  __shared__ float tile[192][68];
  __shared__ float psum[4][64], psq[4][64];
  __shared__ float mu_s[64], inv_s[64];
  const int tid = threadIdx.x;
  const int p0 = blockIdx.x * 64;
  for (int idx = tid; idx < 192 * 16; idx += 256) {
    int c = idx >> 4, p4 = idx & 15;
    f32x4 v = *(const f32x4*)(x + (size_t)c * HW_ + p0 + p4 * 4);
    *(f32x4*)&tile[c][p4 * 4] = v;
  }
  __syncthreads();
  const int tx = tid & 63, ty = tid >> 6;
  float s = 0.f, s2 = 0.f;
  for (int c = ty * 48; c < ty * 48 + 48; c++) {
    float v = tile[c][tx]; s += v; s2 += v * v;
  }
  psum[ty][tx] = s; psq[ty][tx] = s2;
  __syncthreads();
  if (ty == 0) {
    float ts = psum[0][tx] + psum[1][tx] + psum[2][tx] + psum[3][tx];
    float ts2 = psq[0][tx] + psq[1][tx] + psq[2][tx] + psq[3][tx];
    float mu = ts * (1.f / 192.f);
    float var = ts2 * (1.f / 192.f) - mu * mu;
    mu_s[tx] = mu; inv_s[tx] = rsqrtf(var + 1e-5f);
  }
  __syncthreads();
  for (int idx = tid; idx < 64 * 24; idx += 256) {
    int c8 = idx % 24, p = idx / 24;
    float mu = mu_s[p], inv = inv_s[p];
    Pack8 pk;
    #pragma unroll
    for (int u = 0; u < 8; u++) {
      int c = c8 * 8 + u;
      pk.h[u] = __float2bfloat16((tile[c][p] - mu) * inv * w[c] + bi[c]);
    }
    *(i32x4*)&yt[(size_t)(p0 + p) * 192 + c8 * 8] = pk.v;
  }
}

// ---- B-stationary MFMA GEMM: D[M][HW] = A[M][192] @ B[HW][192]^T -----------
// grid (HW/128, batch). B panel (128x192) in LDS (XOR-swizzled), loaded ONCE;
// A fragments double-buffered in registers (named sets, 2x-unrolled loop).
// No barriers in the M-loop (stores never drained at a barrier).
// EPI=0: bf16 out. EPI=1: fp32 out + residual C.
template <int EPI>
__global__ __launch_bounds__(256) void gemm_bstat(
    const __hip_bfloat16* __restrict__ A, const __hip_bfloat16* __restrict__ Bg,
    const float* __restrict__ Cres, void* __restrict__ Dout,
    int Mtiles, size_t Bstr, size_t Cstr, size_t Dstr) {
  const int z = blockIdx.y;
  const __hip_bfloat16* B = Bg + (size_t)z * Bstr;
  const int col0 = blockIdx.x * 128;
  __shared__ __align__(16) __hip_bfloat16 Bs[128][192];
  const int tid = threadIdx.x;
  const int wave = tid >> 6, lane = tid & 63;
  const int quad = lane >> 4, lr = lane & 15;
  const int wm = (wave & 1) * 32, wn = (wave >> 1) * 64;
  const int lrx = lr & 7;                      // read-side XOR (row&7 == lrx)

  const __hip_bfloat16* Ar0 = A + (size_t)(wm + lr) * 192 + quad * 8;
  const __hip_bfloat16* Ar1 = A + (size_t)(wm + 16 + lr) * 192 + quad * 8;

  bf16x8 p0[6], p1[6], q0[6], q1[6];           // two named A-register sets

  auto loadA = [&](bf16x8 (&r0)[6], bf16x8 (&r1)[6], int mt) {
    const size_t abase = (size_t)mt * (64 * 192);
    #pragma unroll
    for (int kc = 0; kc < 6; kc++) {
      r0[kc] = *(const bf16x8*)(Ar0 + abase + kc * 32);
      r1[kc] = *(const bf16x8*)(Ar1 + abase + kc * 32);
    }
  };

  auto computeStore = [&](const bf16x8 (&r0)[6], const bf16x8 (&r1)[6], int mt) {
    f32x4 acc[2][4];
    #pragma unroll
    for (int i = 0; i < 2; i++)
      #pragma unroll
      for (int j = 0; j < 4; j++) acc[i][j] = (f32x4){0.f, 0.f, 0.f, 0.f};
    #pragma unroll
    for (int kc = 0; kc < 6; kc++) {
      const int chq = ((kc * 4 + quad) ^ lrx) * 8;
      #pragma unroll
      for (int j = 0; j < 4; j++) {
        bf16x8 bb = *(const bf16x8*)&Bs[wn + j * 16 + lr][chq];
        acc[0][j] = __builtin_amdgcn_mfma_f32_16x16x32_bf16(r0[kc], bb, acc[0][j], 0, 0, 0);
        acc[1][j] = __builtin_amdgcn_mfma_f32_16x16x32_bf16(r1[kc], bb, acc[1][j], 0, 0, 0);
      }
    }
    const int row0 = mt * 64;
    #pragma unroll
    for (int i = 0; i < 2; i++) {
      #pragma unroll
      for (int r = 0; r < 4; r++) {
        const int gm = row0 + wm + i * 16 + quad * 4 + r;
        const size_t base = (size_t)gm * HW_ + col0 + wn + lr;
        if (EPI == 0) {
          __hip_bfloat16* dp = (__hip_bfloat16*)Dout + (size_t)z * Dstr + base;
          #pragma unroll
          for (int j = 0; j < 4; j++) dp[j * 16] = __float2bfloat16(acc[i][j][r]);
        } else {
          float* dp = (float*)Dout + (size_t)z * Dstr + base;
          const float* cp = Cres + (size_t)z * Cstr + base;
          #pragma unroll
          for (int j = 0; j < 4; j++) dp[j * 16] = acc[i][j][r] + cp[j * 16];
        }
      }
    }
  };

  // A tile-0 prefetch first: overlaps the B-panel staging below.
  loadA(p0, p1, 0);

  // --- load B panel (once), swizzled ---
  const int arow = tid >> 3, ach = tid & 7;    // 32 rows x 8 chunks
  const int achs = ach ^ (arow & 7);
  #pragma unroll
  for (int l = 0; l < 4; l++) {
    const int row = arow + 32 * l;
    const __hip_bfloat16* bp = B + (size_t)(col0 + row) * 192;
    #pragma unroll
    for (int j = 0; j < 3; j++) {
      i32x4 v = *(const i32x4*)(bp + (ach + 8 * j) * 8);
      *(i32x4*)&Bs[row][(achs + 8 * j) * 8] = v;
    }
  }
  __syncthreads();

  int mt = 0;
  for (; mt + 2 <= Mtiles; mt += 2) {
    loadA(q0, q1, mt + 1);                     // prefetch tile mt+1
    computeStore(p0, p1, mt);                  // MFMAs hide the loads
    if (mt + 2 < Mtiles) loadA(p0, p1, mt + 2);
    computeStore(q0, q1, mt + 1);
  }
  if (mt < Mtiles) computeStore(p0, p1, mt);   // odd-count tail
}

// ---- MFMA GEMM: D[M][N] = A[M][K] @ B_t[N][K]^T (+res); z = batch ----------
// (kept for w_out; XOR-swizzled LDS, no pad)
template <int EPI>
__global__ __launch_bounds__(256) void mfma_gemm(
    const __hip_bfloat16* __restrict__ A, const __hip_bfloat16* __restrict__ Bg,
    const float* __restrict__ Cres, void* __restrict__ Dout,
    int M, int N, int K, size_t Bstr, size_t Cstr, size_t Dstr) {
  const int z = blockIdx.z;
  const __hip_bfloat16* B = Bg + (size_t)z * Bstr;
  const float* C = Cres ? Cres + (size_t)z * Cstr : nullptr;
  __shared__ __align__(16) __hip_bfloat16 As[64][64];
  __shared__ __align__(16) __hip_bfloat16 Bs[128][64];
  const int tid = threadIdx.x;
  const int wave = tid >> 6, lane = tid & 63;
  const int quad = lane >> 4, lr = lane & 15;
  const int lrx = lr & 7;
  const int wm = (wave & 1) * 32, wn = (wave >> 1) * 64;
  const int row0 = blockIdx.x * 64, col0 = blockIdx.y * 128;

  f32x4 acc[2][4];
  #pragma unroll
  for (int i = 0; i < 2; i++)
    #pragma unroll
    for (int j = 0; j < 4; j++) acc[i][j] = (f32x4){0.f, 0.f, 0.f, 0.f};

  for (int k0 = 0; k0 < K; k0 += 64) {
    #pragma unroll
    for (int l = 0; l < 2; l++) {
      int t = tid + l * 256;
      int row = t >> 3, ch = t & 7;
      i32x4 v = *(const i32x4*)(A + (size_t)(row0 + row) * K + k0 + ch * 8);
      *(i32x4*)&As[row][(ch ^ (row & 7)) * 8] = v;
    }
    #pragma unroll
    for (int l = 0; l < 4; l++) {
      int t = tid + l * 256;
      int row = t >> 3, ch = t & 7;
      i32x4 v = *(const i32x4*)(B + (size_t)(col0 + row) * K + k0 + ch * 8);
      *(i32x4*)&Bs[row][(ch ^ (row & 7)) * 8] = v;
    }
    __syncthreads();
    #pragma unroll
    for (int ks = 0; ks < 2; ks++) {
      const int chq = ((ks * 4 + quad) ^ lrx) * 8;
      bf16x8 a0 = *(const bf16x8*)&As[wm + lr][chq];
      bf16x8 a1 = *(const bf16x8*)&As[wm + 16 + lr][chq];
      #pragma unroll
      for (int j = 0; j < 4; j++) {
        bf16x8 bb = *(const bf16x8*)&Bs[wn + j * 16 + lr][chq];
        acc[0][j] = __builtin_amdgcn_mfma_f32_16x16x32_bf16(a0, bb, acc[0][j], 0, 0, 0);
        acc[1][j] = __builtin_amdgcn_mfma_f32_16x16x32_bf16(a1, bb, acc[1][j], 0, 0, 0);
      }
    }
    __syncthreads();
  }

  #pragma unroll
  for (int i = 0; i < 2; i++) {
    #pragma unroll
    for (int r = 0; r < 4; r++) {
      int gm = row0 + wm + i * 16 + quad * 4 + r;
      if (gm >= M) continue;
      #pragma unroll
      for (int j = 0; j < 4; j++) {
        int gn = col0 + wn + j * 16 + lr;
        size_t idx = (size_t)gm * N + gn;
        if (EPI == 0) {
          (((__hip_bfloat16*)Dout) + (size_t)z * Dstr)[idx] = __float2bfloat16(acc[i][j][r]);
        } else {
          (((float*)Dout) + (size_t)z * Dstr)[idx] = acc[i][j][r] + C[idx];
        }
      }
    }
  }
}

// ---- depthwise 3x3 (8 px/thread) + fused q,k sum-of-squares partials -------
// boundary pixels via __shfl (row groups are 16 consecutive lanes)
__global__ __launch_bounds__(256) void dw_kernel(
    const __hip_bfloat16* __restrict__ in, const float* __restrict__ wdw,
    __hip_bfloat16* __restrict__ out, float* __restrict__ nrm2p) {
  const int b = blockIdx.z;
  in  += (size_t)b * 576 * HW_;
  out += (size_t)b * 576 * HW_;
  const int c = blockIdx.y;
  const int x8 = threadIdx.x & 15;
  const int y = blockIdx.x * 16 + (threadIdx.x >> 4);
  const __hip_bfloat16* ip = in + (size_t)c * HW_;
  const float* wp = wdw + c * 9;
  float wv[9];
  #pragma unroll
  for (int u = 0; u < 9; u++) wv[u] = wp[u];
  float acc[8];
  #pragma unroll
  for (int j = 0; j < 8; j++) acc[j] = 0.f;
  #pragma unroll
  for (int r = 0; r < 3; r++) {
    const int yy = y + r - 1;
    const bool valid = (yy >= 0) && (yy < 128);
    Pack8 mid;
    if (valid) mid.v = *(const i32x4*)(ip + yy * 128 + x8 * 8);
    else       mid.v = (i32x4){0, 0, 0, 0};
    const int hi = ((i32x4)mid.v)[3];
    const int lo = ((i32x4)mid.v)[0];
    const int lw = __shfl_up(hi, 1, 64);
    const int rw = __shfl_down(lo, 1, 64);
    float row[10];
    row[0] = (x8 > 0) ? (float)(((const __hip_bfloat16*)&lw)[1]) : 0.f;
    #pragma unroll
    for (int u = 0; u < 8; u++) row[1 + u] = (float)mid.h[u];
    row[9] = (x8 < 15) ? (float)(((const __hip_bfloat16*)&rw)[0]) : 0.f;
    const float wl = wv[r * 3], wc = wv[r * 3 + 1], wr = wv[r * 3 + 2];
    #pragma unroll
    for (int j = 0; j < 8; j++)
      acc[j] += wl * row[j] + wc * row[j + 1] + wr * row[j + 2];
  }
  Pack8 o;
  #pragma unroll
  for (int j = 0; j < 8; j++) o.h[j] = __float2bfloat16(acc[j]);
  *(i32x4*)(out + (size_t)c * HW_ + y * 128 + x8 * 8) = o.v;
  if (c < 384) {
    float s = 0.f;
    #pragma unroll
    for (int j = 0; j < 8; j++) s += acc[j] * acc[j];
    #pragma unroll
    for (int off = 32; off > 0; off >>= 1) s += __shfl_down(s, off, 64);
    __shared__ float wsum[4];
    const int lane = threadIdx.x & 63, wvi = threadIdx.x >> 6;
    if (lane == 0) wsum[wvi] = s;
    __syncthreads();
    if (threadIdx.x == 0)
      nrm2p[((size_t)b * 384 + c) * 8 + blockIdx.x] =
          wsum[0] + wsum[1] + wsum[2] + wsum[3];
  }
}

// ---- MFMA Gram partials; grid (8 heads, 32 chunks, 4 batch) ----------------
__global__ __launch_bounds__(256) void gram_kernel(
    const __hip_bfloat16* __restrict__ qkv, float* __restrict__ Gpart) {
  const int b = blockIdx.z;
  qkv   += (size_t)b * 576 * HW_;
  Gpart += (size_t)b * 32 * 8 * 576;
  const int h = blockIdx.x, chunk = blockIdx.y;
  const int tid = threadIdx.x;
  const int w = tid >> 6, lane = tid & 63;
  const int m = lane & 31;
  const int khalf = lane >> 5;
  const __hip_bfloat16* qb = qkv + (size_t)(h * 24) * HW_;
  const __hip_bfloat16* kb = qkv + (size_t)(192 + h * 24) * HW_;
  f32x16 acc;
  #pragma unroll
  for (int i = 0; i < 16; i++) acc[i] = 0.f;
  const int e0 = chunk * 512 + w * 128;
  #pragma unroll
  for (int j = 0; j < 8; j++) {
    const int k0 = e0 + j * 16 + khalf * 8;
    bf16x8 a = *(const bf16x8*)(qb + (size_t)m * HW_ + k0);
    bf16x8 bfr = *(const bf16x8*)(kb + (size_t)m * HW_ + k0);
    acc = __builtin_amdgcn_mfma_f32_32x32x16_bf16(a, bfr, acc, 0, 0, 0);
  }
  __shared__ float gs[4][576];
  #pragma unroll
  for (int r = 0; r < 16; r++) {
    int row = (r & 3) + 8 * (r >> 2) + 4 * khalf;
    if (row < 24 && m < 24) gs[w][row * 24 + m] = acc[r];
  }
  __syncthreads();
  float* gp = Gpart + (size_t)(chunk * 8 + h) * 576;
  for (int t = tid; t < 576; t += 256)
    gp[t] = gs[0][t] + gs[1][t] + gs[2][t] + gs[3][t];
}

// ---- reduce Gpart + nrm2p partials, softmax -> P; grid (8 heads, 4 batch) --
__global__ __launch_bounds__(256) void softmax2_kernel(
    const float* __restrict__ Gpart, const float* __restrict__ nrm2p,
    const float* __restrict__ temp, float* __restrict__ P) {
  const int b = blockIdx.y;
  Gpart += (size_t)b * 32 * 8 * 576;
  nrm2p += (size_t)b * 384 * 8;
  P     += (size_t)b * 8 * 576;
  const int h = blockIdx.x;
  const int tid = threadIdx.x;
  __shared__ float Gs[576];
  __shared__ float nq[24], nk[24];
  for (int t = tid; t < 576; t += 256) {
    float s = 0.f;
    for (int ch = 0; ch < 32; ch++)
      s += Gpart[(size_t)(ch * 8 + h) * 576 + t];
    Gs[t] = s;
  }
  if (tid < 48) {
    const int r = (tid < 24) ? (h * 24 + tid) : (192 + h * 24 + tid - 24);
    float s = 0.f;
    #pragma unroll
    for (int j = 0; j < 8; j++) s += nrm2p[(size_t)r * 8 + j];
    float nv = fmaxf(sqrtf(s), 1e-12f);
    if (tid < 24) nq[tid] = nv; else nk[tid - 24] = nv;
  }
  __syncthreads();
  if (tid < 24) {
    const int d = tid;
    const float tp = temp[h];
    float row[24], mx = -1e30f;
    #pragma unroll
    for (int c = 0; c < 24; c++) {
      float v = Gs[d * 24 + c] * tp / (nq[d] * nk[c]);
      row[c] = v; mx = fmaxf(mx, v);
    }
    float s = 0.f;
    #pragma unroll
    for (int c = 0; c < 24; c++) { float e = expf(row[c] - mx); row[c] = e; s += e; }
    const float inv = 1.f / s;
    #pragma unroll
    for (int c = 0; c < 24; c++) P[h * 576 + d * 24 + c] = row[c] * inv;
  }
}

// ---- out_t[e][h*24+d] = sum_c P[h,d,c]*v[h,c,e]; grid (8, 64, 4) -----------
__global__ __launch_bounds__(256) void pv_kernel(
    const float* __restrict__ P, const __hip_bfloat16* __restrict__ qkv,
    __hip_bfloat16* __restrict__ yt) {
  const int b = blockIdx.z;
  P   += (size_t)b * 8 * 576;
  qkv += (size_t)b * 576 * HW_;
  yt  += (size_t)b * HW_ * 192;
  const int hh = blockIdx.x;
  const int e = blockIdx.y * 256 + threadIdx.x;
  __shared__ float Ps[576];
  for (int t = threadIdx.x; t < 576; t += 256) Ps[t] = P[hh * 576 + t];
  __syncthreads();
  const __hip_bfloat16* vb = qkv + (size_t)(384 + hh * 24) * HW_;
  float acc[24];
  #pragma unroll
  for (int d = 0; d < 24; d++) acc[d] = 0.f;
  for (int c = 0; c < 24; c++) {
    float v = (float)vb[(size_t)c * HW_ + e];
    #pragma unroll
    for (int d = 0; d < 24; d++) acc[d] += Ps[d * 24 + c] * v;
  }
  #pragma unroll
  for (int g = 0; g < 3; g++) {
    Pack8 pk;
    #pragma unroll
    for (int u = 0; u < 8; u++) pk.h[u] = __float2bfloat16(acc[g * 8 + u]);
    *(i32x4*)&yt[(size_t)e * 192 + hh * 24 + g * 8] = pk.v;
  }
}

// ---- FFN depthwise + GELU gate -> transposed gt[p][512], 4-row tiles -------
// grid (64 = yt*2+xh, 16 ch-groups, 2 batch-within-half). Block: 32 ch x
// 4 rows x 64 px. Rolling pass over 6 input rows. LDS 17KB -> ~8 blocks/CU.
__global__ __launch_bounds__(256) void dwg_t_kernel(
    const __hip_bfloat16* __restrict__ hsrc, const float* __restrict__ wdw,
    __hip_bfloat16* __restrict__ gt, int b0) {
  const int z = blockIdx.z;
  const int bb = b0 + z;
  const int yt = blockIdx.x >> 1, xh = blockIdx.x & 1;
  const int cz = blockIdx.y;
  const int tid = threadIdx.x;
  const int cl = tid >> 3, x8 = tid & 7;         // 32 ch x 8 px-groups
  const int c = cz * 32 + cl;
  const int y0 = yt * 4;
  const int pxb = xh * 64 + x8 * 8;              // global px base
  __shared__ __hip_bfloat16 sg[32][266];         // [ch][4*64] pad->266

  const bool active = (c < 510);
  const int ca = active ? c : 0;
  const __hip_bfloat16* ha = hsrc + ((size_t)bb * 1024 + ca) * HW_;
  const __hip_bfloat16* hb = hsrc + ((size_t)bb * 1024 + ca + 510) * HW_;
  float wva[9], wvb[9];
  #pragma unroll
  for (int u = 0; u < 9; u++) {
    wva[u] = active ? wdw[c * 9 + u] : 0.f;
    wvb[u] = active ? wdw[(c + 510) * 9 + u] : 0.f;
  }

  float aA[3][8], aB[3][8];
  #pragma unroll
  for (int s = 0; s < 3; s++)
    #pragma unroll
    for (int j = 0; j < 8; j++) { aA[s][j] = 0.f; aB[s][j] = 0.f; }

  #pragma unroll
  for (int i = 0; i < 6; i++) {
    const int ry = y0 - 1 + i;
    float ra[10], rb[10];
    if (ry >= 0 && ry < 128) {
      const int off = ry * 128 + pxb;
      Pack8 ma; ma.v = *(const i32x4*)(ha + off);
      Pack8 mb; mb.v = *(const i32x4*)(hb + off);
      ra[0] = (pxb > 0) ? (float)ha[off - 1] : 0.f;
      rb[0] = (pxb > 0) ? (float)hb[off - 1] : 0.f;
      #pragma unroll
      for (int u = 0; u < 8; u++) { ra[1 + u] = (float)ma.h[u]; rb[1 + u] = (float)mb.h[u]; }
      ra[9] = (pxb < 120) ? (float)ha[off + 8] : 0.f;
      rb[9] = (pxb < 120) ? (float)hb[off + 8] : 0.f;
    } else {
      #pragma unroll
      for (int u = 0; u < 10; u++) { ra[u] = 0.f; rb[u] = 0.f; }
    }
    // input row ry feeds output rows lo = i-r (weight-row r)
    #pragma unroll
    for (int r = 0; r < 3; r++) {
      const int lo = i - r;
      if (lo < 0 || lo >= 4) continue;
      const int s = lo % 3;
      const float a0 = wva[r * 3], a1 = wva[r * 3 + 1], a2 = wva[r * 3 + 2];
      const float b0w = wvb[r * 3], b1 = wvb[r * 3 + 1], b2 = wvb[r * 3 + 2];
      #pragma unroll
      for (int j = 0; j < 8; j++) {
        aA[s][j] += a0 * ra[j] + a1 * ra[j + 1] + a2 * ra[j + 2];
        aB[s][j] += b0w * rb[j] + b1 * rb[j + 1] + b2 * rb[j + 2];
      }
    }
    // output row lo = i-2 is complete: gate + stage to LDS, recycle slot
    {
      const int lo = i - 2;
      if (lo >= 0 && lo < 4) {
        const int s = lo % 3;
        Pack8 o;
        #pragma unroll
        for (int j = 0; j < 8; j++) {
          float v = aA[s][j];
          float ge = 0.5f * v * (1.f + erff(v * 0.70710678118654752f));
          o.h[j] = __float2bfloat16(ge * aB[s][j]);
          aA[s][j] = 0.f; aB[s][j] = 0.f;
        }
        *(i32x4*)&sg[cl][lo * 64 + x8 * 8] = o.v;
      }
    }
  }
  __syncthreads();
  // transposed write: 256 local px x 32 ch; 4 lanes cover one 64B px segment
  const int sp = tid >> 2, ch0 = (tid & 3) * 8;
  #pragma unroll
  for (int k = 0; k < 4; k++) {
    Pack8 o;
    #pragma unroll
    for (int u = 0; u < 8; u++) o.h[u] = sg[ch0 + u][k * 64 + sp];
    const int gp = (y0 + k) * 128 + xh * 64 + sp;
    *(i32x4*)&gt[((size_t)z * HW_ + gp) * 512 + cz * 32 + ch0] = o.v;
  }
}

// ---------------------------------------------------------------------------
extern "C" void kernel_launch(void* const* d_in, const int* in_sizes, int n_in,
                              void* d_out, int out_size, void* d_ws, size_t ws_size,
                              hipStream_t stream) {
  const float* x     = (const float*)d_in[0];
  const float* temp  = (const float*)d_in[1];
  const float* ln1w  = (const float*)d_in[2];
  const float* ln1b  = (const float*)d_in[3];
  const float* ln2w  = (const float*)d_in[4];
  const float* ln2b  = (const float*)d_in[5];
  const float* wqkv  = (const float*)d_in[6];
  const float* wqkvdw= (const float*)d_in[7];
  const float* wproj = (const float*)d_in[8];
  const float* win   = (const float*)d_in[9];
  const float* wdw   = (const float*)d_in[10];
  const float* wout  = (const float*)d_in[11];
  float* out = (float*)d_out;
  char* ws = (char*)d_ws;

  const int HW = 16384;
  const size_t HWC = (size_t)192 * HW;

  __hip_bfloat16* yt    = (__hip_bfloat16*)(ws + 0);
  __hip_bfloat16* qkva  = (__hip_bfloat16*)(ws + 25165824);
  __hip_bfloat16* qkvb  = (__hip_bfloat16*)(ws + 100663296);
  __hip_bfloat16* hbuf  = (__hip_bfloat16*)(ws + 25165824);   // aliases dead qkva/qkvb
  float*          xa    = (float*)(ws + 176160768);
  __hip_bfloat16* gt    = (__hip_bfloat16*)(ws + 226492416);  // 2 half-batches
  __hip_bfloat16* wqkvB = (__hip_bfloat16*)(ws + 260046848);
  __hip_bfloat16* wprojB= (__hip_bfloat16*)(ws + 260268032);
  __hip_bfloat16* winB  = (__hip_bfloat16*)(ws + 260341760);
  __hip_bfloat16* woutB = (__hip_bfloat16*)(ws + 260734976);
  float*          nrm2p = (float*)(ws + 260931584);
  float*          Gpart = (float*)(ws + 260980736);
  float*          P     = (float*)(ws + 263340032);

  convert_weights<<<768, 256, 0, stream>>>(wqkv, wproj, win, wout,
                                           wqkvB, wprojB, winB, woutB);

  // 1. yt = LN1(x), all batches
  ln_t_kernel<<<dim3(256, 4), 256, 0, stream>>>(x, ln1w, ln1b, yt);
  // 2. qkva = w_qkv @ y   (576 x 16384) x4 — B-stationary, barrier-free
  gemm_bstat<0><<<dim3(128, 4), 256, 0, stream>>>(
      wqkvB, yt, nullptr, qkva, 9, (size_t)HW * 192, 0, (size_t)576 * HW);
  // 3. qkvb = dwconv3x3(qkva) + nrm2 partials
  dw_kernel<<<dim3(8, 576, 4), 256, 0, stream>>>(qkva, wqkvdw, qkvb, nrm2p);
  // 4. Gram partials via MFMA
  gram_kernel<<<dim3(8, 32, 4), 256, 0, stream>>>(qkvb, Gpart);
  // 5. P = softmax(reduce(Gpart) * temp / (|q||k|))
  softmax2_kernel<<<dim3(8, 4), 256, 0, stream>>>(Gpart, nrm2p, temp, P);
  // 6. yt = (P @ v)^T bf16
  pv_kernel<<<dim3(8, 64, 4), 256, 0, stream>>>(P, qkvb, yt);
  // 7. xa = x + w_proj @ pv — B-stationary with residual epilogue
  gemm_bstat<1><<<dim3(128, 4), 256, 0, stream>>>(
      wprojB, yt, x, xa, 3, (size_t)HW * 192, HWC, HWC);
  // 8. yt = LN2(xa)
  ln_t_kernel<<<dim3(256, 4), 256, 0, stream>>>(xa, ln2w, ln2b, yt);
  // 9. hbuf = w_in @ y   (1024 x 16384) x4 — B-stationary (rows>=1020 zero)
  gemm_bstat<0><<<dim3(128, 4), 256, 0, stream>>>(
      winB, yt, nullptr, hbuf, 16, (size_t)HW * 192, 0, (size_t)1024 * HW);
  // 10-13. FFN tail in two half-batches: gate(+transpose) then w_out GEMM
  for (int half = 0; half < 2; half++) {
    const int b0 = half * 2;
    dwg_t_kernel<<<dim3(64, 16, 2), 256, 0, stream>>>(hbuf, wdw, gt, b0);
    mfma_gemm<1><<<dim3(3, 128, 2), 256, 0, stream>>>(
        woutB, gt, xa + (size_t)b0 * HWC, out + (size_t)b0 * HWC,
        192, HW, 512, (size_t)HW * 512, HWC, HWC);
  }
}

// Round 7
// 477.096 us; speedup vs baseline: 1.0667x; 1.0667x over previous
//
#include <hip/hip_runtime.h>
#include <hip/hip_bf16.h>
#include <math.h>

// ---------------------------------------------------------------------------
// Round 14 = r12 base + gemm_bstat re-tiled to 64-col B-panels.
// r10/r13 showed barrier-free variants lose (83/70 µs vs 46); the shared
// constraint was the 512-block grid = 2 blocks/CU (grid-limited occupancy
// 17%). 64-col panels -> 1024 blocks = 4/CU, LDS 73.7->49.2 KB (3 resident),
// 12 waves/CU: per-tile 8KB store drains overlap across 3 blocks.
// B still fetched exactly once; extra A reads are L2-resident weights.
//
// ws layout (bytes):
//   yt4    @ 0            25,165,824  bf16 [b][p][192]
//   qkva4  @ 25,165,824   75,497,472  bf16 [b][576][p]
//   qkvb4  @ 100,663,296  75,497,472  bf16 [b][576][p]
//   hbuf4  @ 25,165,824  134,217,728  bf16 [b][1024][p]  (aliases dead qkva/qkvb)
//   xa4    @ 176,160,768  50,331,648  fp32 [b][192][p]
//   gt2    @ 226,492,416  33,554,432  bf16 [z][p][512]   (half-batch)
//   wqkvB  @ 260,046,848     221,184
//   wprojB @ 260,268,032      73,728
//   winB   @ 260,341,760     393,216  (1024x192, rows >=1020 zero)
//   woutB  @ 260,734,976     196,608  (192x512, cols >=510 zero)
//   nrm2p  @ 260,931,584      49,152  fp32 [b][384][8]
//   Gpart  @ 260,980,736   2,359,296  fp32 [b][32][8][576]
//   P      @ 263,340,032      73,728  fp32 [b][8][576]
// total 263,413,760 <= 268,435,456. No atomics, no memsets.
// ---------------------------------------------------------------------------

#define HW_ 16384

typedef __attribute__((ext_vector_type(8))) short bf16x8;
typedef __attribute__((ext_vector_type(4))) float f32x4;
typedef __attribute__((ext_vector_type(16))) float f32x16;
typedef __attribute__((ext_vector_type(4))) int i32x4;

union Pack8 { __hip_bfloat16 h[8]; i32x4 v; };

// ---- weight fp32 -> bf16 conversion (with padding) -------------------------
__global__ __launch_bounds__(256) void convert_weights(
    const float* __restrict__ wqkv, const float* __restrict__ wproj,
    const float* __restrict__ win, const float* __restrict__ wout,
    __hip_bfloat16* __restrict__ oq, __hip_bfloat16* __restrict__ op,
    __hip_bfloat16* __restrict__ oi, __hip_bfloat16* __restrict__ oo) {
  const int i = blockIdx.x * 256 + threadIdx.x;
  if (i < 110592) oq[i] = __float2bfloat16(wqkv[i]);            // 576x192
  if (i < 36864)  op[i] = __float2bfloat16(wproj[i]);           // 192x192
  if (i < 196608) {                                             // 1024x192 pad
    int m = i / 192, k = i - m * 192;
    oi[i] = __float2bfloat16(m < 1020 ? win[m * 192 + k] : 0.f);
  }
  if (i < 98304) {                                              // 192x512 pad
    int m = i >> 9, k = i & 511;
    oo[i] = __float2bfloat16(k < 510 ? wout[m * 510 + k] : 0.f);
  }
}

// ---- channel LN -> transposed bf16 output [p][192]; grid (256, batch) ------
__global__ __launch_bounds__(256) void ln_t_kernel(
    const float* __restrict__ x, const float* __restrict__ w,
    const float* __restrict__ bi, __hip_bfloat16* __restrict__ yt) {
  const int b = blockIdx.y;
  x += (size_t)b * 192 * HW_;
  yt += (size_t)b * HW_ * 192;
  __shared__ float tile[192][68];
  __shared__ float psum[4][64], psq[4][64];
  __shared__ float mu_s[64], inv_s[64];
  const int tid = threadIdx.x;
  const int p0 = blockIdx.x * 64;
  for (int idx = tid; idx < 192 * 16; idx += 256) {
    int c = idx >> 4, p4 = idx & 15;
    f32x4 v = *(const f32x4*)(x + (size_t)c * HW_ + p0 + p4 * 4);
    *(f32x4*)&tile[c][p4 * 4] = v;
  }
  __syncthreads();
  const int tx = tid & 63, ty = tid >> 6;
  float s = 0.f, s2 = 0.f;
  for (int c = ty * 48; c < ty * 48 + 48; c++) {
    float v = tile[c][tx]; s += v; s2 += v * v;
  }
  psum[ty][tx] = s; psq[ty][tx] = s2;
  __syncthreads();
  if (ty == 0) {
    float ts = psum[0][tx] + psum[1][tx] + psum[2][tx] + psum[3][tx];
    float ts2 = psq[0][tx] + psq[1][tx] + psq[2][tx] + psq[3][tx];
    float mu = ts * (1.f / 192.f);
    float var = ts2 * (1.f / 192.f) - mu * mu;
    mu_s[tx] = mu; inv_s[tx] = rsqrtf(var + 1e-5f);
  }
  __syncthreads();
  for (int idx = tid; idx < 64 * 24; idx += 256) {
    int c8 = idx % 24, p = idx / 24;
    float mu = mu_s[p], inv = inv_s[p];
    Pack8 pk;
    #pragma unroll
    for (int u = 0; u < 8; u++) {
      int c = c8 * 8 + u;
      pk.h[u] = __float2bfloat16((tile[c][p] - mu) * inv * w[c] + bi[c]);
    }
    *(i32x4*)&yt[(size_t)(p0 + p) * 192 + c8 * 8] = pk.v;
  }
}

// ---- B-stationary MFMA GEMM, 64-col panels: D[M][HW] = A[M][192]@B[HW][192]^T
// grid (HW/64, batch). B panel (64x192) in LDS once; M-loop with A
// reg-prefetch + LDS staging (r8/r12-proven 2-barrier structure).
// XOR-swizzled LDS, conflict-free b128. EPI=0: bf16 out. EPI=1: fp32 + res C.
template <int EPI>
__global__ __launch_bounds__(256) void gemm_bstat(
    const __hip_bfloat16* __restrict__ A, const __hip_bfloat16* __restrict__ Bg,
    const float* __restrict__ Cres, void* __restrict__ Dout,
    int Mtiles, size_t Bstr, size_t Cstr, size_t Dstr) {
  const int z = blockIdx.y;
  const __hip_bfloat16* B = Bg + (size_t)z * Bstr;
  const int col0 = blockIdx.x * 64;
  __shared__ __align__(16) __hip_bfloat16 Bs[64][192];
  __shared__ __align__(16) __hip_bfloat16 As[64][192];
  const int tid = threadIdx.x;
  const int wave = tid >> 6, lane = tid & 63;
  const int quad = lane >> 4, lr = lane & 15;
  const int wm = (wave & 1) * 32, wn = (wave >> 1) * 32;
  const int lrx = lr & 7;                      // read-side XOR (row&7 == lrx)

  const int arow = tid >> 3, ach = tid & 7;    // staging coords (32 rows x 8 ch)
  const int achs = ach ^ (arow & 7);           // swizzled chunk base

  // --- load B panel (once), swizzled ---
  #pragma unroll
  for (int l = 0; l < 2; l++) {
    const int row = arow + 32 * l;
    const __hip_bfloat16* bp = B + (size_t)(col0 + row) * 192;
    #pragma unroll
    for (int j = 0; j < 3; j++) {
      i32x4 v = *(const i32x4*)(bp + (ach + 8 * j) * 8);
      *(i32x4*)&Bs[row][(achs + 8 * j) * 8] = v;
    }
  }
  // --- prefetch A tile 0 to regs ---
  i32x4 areg[6];
  #pragma unroll
  for (int l = 0; l < 2; l++)
    #pragma unroll
    for (int j = 0; j < 3; j++)
      areg[l * 3 + j] = *(const i32x4*)(
          A + (size_t)(arow + 32 * l) * 192 + (ach + 8 * j) * 8);
  // --- stage A tile 0 ---
  #pragma unroll
  for (int l = 0; l < 2; l++)
    #pragma unroll
    for (int j = 0; j < 3; j++)
      *(i32x4*)&As[arow + 32 * l][(achs + 8 * j) * 8] = areg[l * 3 + j];
  __syncthreads();

  for (int mt = 0; mt < Mtiles; mt++) {
    const int row0 = mt * 64;
    if (mt + 1 < Mtiles) {                     // issue next A loads (L2-hit)
      const __hip_bfloat16* ap = A + (size_t)(mt + 1) * 64 * 192;
      #pragma unroll
      for (int l = 0; l < 2; l++)
        #pragma unroll
        for (int j = 0; j < 3; j++)
          areg[l * 3 + j] = *(const i32x4*)(
              ap + (size_t)(arow + 32 * l) * 192 + (ach + 8 * j) * 8);
    }
    f32x4 acc[2][2];
    #pragma unroll
    for (int i = 0; i < 2; i++)
      #pragma unroll
      for (int j = 0; j < 2; j++) acc[i][j] = (f32x4){0.f, 0.f, 0.f, 0.f};
    #pragma unroll
    for (int kc = 0; kc < 6; kc++) {
      const int chq = ((kc * 4 + quad) ^ lrx) * 8;
      bf16x8 a0 = *(const bf16x8*)&As[wm + lr][chq];
      bf16x8 a1 = *(const bf16x8*)&As[wm + 16 + lr][chq];
      #pragma unroll
      for (int j = 0; j < 2; j++) {
        bf16x8 bb = *(const bf16x8*)&Bs[wn + j * 16 + lr][chq];
        acc[0][j] = __builtin_amdgcn_mfma_f32_16x16x32_bf16(a0, bb, acc[0][j], 0, 0, 0);
        acc[1][j] = __builtin_amdgcn_mfma_f32_16x16x32_bf16(a1, bb, acc[1][j], 0, 0, 0);
      }
    }
    #pragma unroll
    for (int i = 0; i < 2; i++)
      #pragma unroll
      for (int r = 0; r < 4; r++) {
        const int gm = row0 + wm + i * 16 + quad * 4 + r;
        const size_t base = (size_t)gm * HW_ + col0 + wn + lr;
        if (EPI == 0) {
          __hip_bfloat16* dp = (__hip_bfloat16*)Dout + (size_t)z * Dstr + base;
          #pragma unroll
          for (int j = 0; j < 2; j++) dp[j * 16] = __float2bfloat16(acc[i][j][r]);
        } else {
          float* dp = (float*)Dout + (size_t)z * Dstr + base;
          const float* cp = Cres + (size_t)z * Cstr + base;
          #pragma unroll
          for (int j = 0; j < 2; j++) dp[j * 16] = acc[i][j][r] + cp[j * 16];
        }
      }
    __syncthreads();                           // all waves done reading As
    if (mt + 1 < Mtiles) {
      #pragma unroll
      for (int l = 0; l < 2; l++)
        #pragma unroll
        for (int j = 0; j < 3; j++)
          *(i32x4*)&As[arow + 32 * l][(achs + 8 * j) * 8] = areg[l * 3 + j];
      __syncthreads();
    }
  }
}

// ---- MFMA GEMM: D[M][N] = A[M][K] @ B_t[N][K]^T (+res); z = batch ----------
// (kept for w_out; XOR-swizzled LDS, no pad)
template <int EPI>
__global__ __launch_bounds__(256) void mfma_gemm(
    const __hip_bfloat16* __restrict__ A, const __hip_bfloat16* __restrict__ Bg,
    const float* __restrict__ Cres, void* __restrict__ Dout,
    int M, int N, int K, size_t Bstr, size_t Cstr, size_t Dstr) {
  const int z = blockIdx.z;
  const __hip_bfloat16* B = Bg + (size_t)z * Bstr;
  const float* C = Cres ? Cres + (size_t)z * Cstr : nullptr;
  __shared__ __align__(16) __hip_bfloat16 As[64][64];
  __shared__ __align__(16) __hip_bfloat16 Bs[128][64];
  const int tid = threadIdx.x;
  const int wave = tid >> 6, lane = tid & 63;
  const int quad = lane >> 4, lr = lane & 15;
  const int lrx = lr & 7;
  const int wm = (wave & 1) * 32, wn = (wave >> 1) * 64;
  const int row0 = blockIdx.x * 64, col0 = blockIdx.y * 128;

  f32x4 acc[2][4];
  #pragma unroll
  for (int i = 0; i < 2; i++)
    #pragma unroll
    for (int j = 0; j < 4; j++) acc[i][j] = (f32x4){0.f, 0.f, 0.f, 0.f};

  for (int k0 = 0; k0 < K; k0 += 64) {
    #pragma unroll
    for (int l = 0; l < 2; l++) {
      int t = tid + l * 256;
      int row = t >> 3, ch = t & 7;
      i32x4 v = *(const i32x4*)(A + (size_t)(row0 + row) * K + k0 + ch * 8);
      *(i32x4*)&As[row][(ch ^ (row & 7)) * 8] = v;
    }
    #pragma unroll
    for (int l = 0; l < 4; l++) {
      int t = tid + l * 256;
      int row = t >> 3, ch = t & 7;
      i32x4 v = *(const i32x4*)(B + (size_t)(col0 + row) * K + k0 + ch * 8);
      *(i32x4*)&Bs[row][(ch ^ (row & 7)) * 8] = v;
    }
    __syncthreads();
    #pragma unroll
    for (int ks = 0; ks < 2; ks++) {
      const int chq = ((ks * 4 + quad) ^ lrx) * 8;
      bf16x8 a0 = *(const bf16x8*)&As[wm + lr][chq];
      bf16x8 a1 = *(const bf16x8*)&As[wm + 16 + lr][chq];
      #pragma unroll
      for (int j = 0; j < 4; j++) {
        bf16x8 bb = *(const bf16x8*)&Bs[wn + j * 16 + lr][chq];
        acc[0][j] = __builtin_amdgcn_mfma_f32_16x16x32_bf16(a0, bb, acc[0][j], 0, 0, 0);
        acc[1][j] = __builtin_amdgcn_mfma_f32_16x16x32_bf16(a1, bb, acc[1][j], 0, 0, 0);
      }
    }
    __syncthreads();
  }

  #pragma unroll
  for (int i = 0; i < 2; i++) {
    #pragma unroll
    for (int r = 0; r < 4; r++) {
      int gm = row0 + wm + i * 16 + quad * 4 + r;
      if (gm >= M) continue;
      #pragma unroll
      for (int j = 0; j < 4; j++) {
        int gn = col0 + wn + j * 16 + lr;
        size_t idx = (size_t)gm * N + gn;
        if (EPI == 0) {
          (((__hip_bfloat16*)Dout) + (size_t)z * Dstr)[idx] = __float2bfloat16(acc[i][j][r]);
        } else {
          (((float*)Dout) + (size_t)z * Dstr)[idx] = acc[i][j][r] + C[idx];
        }
      }
    }
  }
}

// ---- depthwise 3x3 (8 px/thread) + fused q,k sum-of-squares partials -------
// boundary pixels via __shfl (row groups are 16 consecutive lanes)
__global__ __launch_bounds__(256) void dw_kernel(
    const __hip_bfloat16* __restrict__ in, const float* __restrict__ wdw,
    __hip_bfloat16* __restrict__ out, float* __restrict__ nrm2p) {
  const int b = blockIdx.z;
  in  += (size_t)b * 576 * HW_;
  out += (size_t)b * 576 * HW_;
  const int c = blockIdx.y;
  const int x8 = threadIdx.x & 15;
  const int y = blockIdx.x * 16 + (threadIdx.x >> 4);
  const __hip_bfloat16* ip = in + (size_t)c * HW_;
  const float* wp = wdw + c * 9;
  float wv[9];
  #pragma unroll
  for (int u = 0; u < 9; u++) wv[u] = wp[u];
  float acc[8];
  #pragma unroll
  for (int j = 0; j < 8; j++) acc[j] = 0.f;
  #pragma unroll
  for (int r = 0; r < 3; r++) {
    const int yy = y + r - 1;
    const bool valid = (yy >= 0) && (yy < 128);
    Pack8 mid;
    if (valid) mid.v = *(const i32x4*)(ip + yy * 128 + x8 * 8);
    else       mid.v = (i32x4){0, 0, 0, 0};
    const int hi = ((i32x4)mid.v)[3];
    const int lo = ((i32x4)mid.v)[0];
    const int lw = __shfl_up(hi, 1, 64);
    const int rw = __shfl_down(lo, 1, 64);
    float row[10];
    row[0] = (x8 > 0) ? (float)(((const __hip_bfloat16*)&lw)[1]) : 0.f;
    #pragma unroll
    for (int u = 0; u < 8; u++) row[1 + u] = (float)mid.h[u];
    row[9] = (x8 < 15) ? (float)(((const __hip_bfloat16*)&rw)[0]) : 0.f;
    const float wl = wv[r * 3], wc = wv[r * 3 + 1], wr = wv[r * 3 + 2];
    #pragma unroll
    for (int j = 0; j < 8; j++)
      acc[j] += wl * row[j] + wc * row[j + 1] + wr * row[j + 2];
  }
  Pack8 o;
  #pragma unroll
  for (int j = 0; j < 8; j++) o.h[j] = __float2bfloat16(acc[j]);
  *(i32x4*)(out + (size_t)c * HW_ + y * 128 + x8 * 8) = o.v;
  if (c < 384) {
    float s = 0.f;
    #pragma unroll
    for (int j = 0; j < 8; j++) s += acc[j] * acc[j];
    #pragma unroll
    for (int off = 32; off > 0; off >>= 1) s += __shfl_down(s, off, 64);
    __shared__ float wsum[4];
    const int lane = threadIdx.x & 63, wvi = threadIdx.x >> 6;
    if (lane == 0) wsum[wvi] = s;
    __syncthreads();
    if (threadIdx.x == 0)
      nrm2p[((size_t)b * 384 + c) * 8 + blockIdx.x] =
          wsum[0] + wsum[1] + wsum[2] + wsum[3];
  }
}

// ---- MFMA Gram partials; grid (8 heads, 32 chunks, 4 batch) ----------------
__global__ __launch_bounds__(256) void gram_kernel(
    const __hip_bfloat16* __restrict__ qkv, float* __restrict__ Gpart) {
  const int b = blockIdx.z;
  qkv   += (size_t)b * 576 * HW_;
  Gpart += (size_t)b * 32 * 8 * 576;
  const int h = blockIdx.x, chunk = blockIdx.y;
  const int tid = threadIdx.x;
  const int w = tid >> 6, lane = tid & 63;
  const int m = lane & 31;
  const int khalf = lane >> 5;
  const __hip_bfloat16* qb = qkv + (size_t)(h * 24) * HW_;
  const __hip_bfloat16* kb = qkv + (size_t)(192 + h * 24) * HW_;
  f32x16 acc;
  #pragma unroll
  for (int i = 0; i < 16; i++) acc[i] = 0.f;
  const int e0 = chunk * 512 + w * 128;
  #pragma unroll
  for (int j = 0; j < 8; j++) {
    const int k0 = e0 + j * 16 + khalf * 8;
    bf16x8 a = *(const bf16x8*)(qb + (size_t)m * HW_ + k0);
    bf16x8 bfr = *(const bf16x8*)(kb + (size_t)m * HW_ + k0);
    acc = __builtin_amdgcn_mfma_f32_32x32x16_bf16(a, bfr, acc, 0, 0, 0);
  }
  __shared__ float gs[4][576];
  #pragma unroll
  for (int r = 0; r < 16; r++) {
    int row = (r & 3) + 8 * (r >> 2) + 4 * khalf;
    if (row < 24 && m < 24) gs[w][row * 24 + m] = acc[r];
  }
  __syncthreads();
  float* gp = Gpart + (size_t)(chunk * 8 + h) * 576;
  for (int t = tid; t < 576; t += 256)
    gp[t] = gs[0][t] + gs[1][t] + gs[2][t] + gs[3][t];
}

// ---- reduce Gpart + nrm2p partials, softmax -> P; grid (8 heads, 4 batch) --
__global__ __launch_bounds__(256) void softmax2_kernel(
    const float* __restrict__ Gpart, const float* __restrict__ nrm2p,
    const float* __restrict__ temp, float* __restrict__ P) {
  const int b = blockIdx.y;
  Gpart += (size_t)b * 32 * 8 * 576;
  nrm2p += (size_t)b * 384 * 8;
  P     += (size_t)b * 8 * 576;
  const int h = blockIdx.x;
  const int tid = threadIdx.x;
  __shared__ float Gs[576];
  __shared__ float nq[24], nk[24];
  for (int t = tid; t < 576; t += 256) {
    float s = 0.f;
    for (int ch = 0; ch < 32; ch++)
      s += Gpart[(size_t)(ch * 8 + h) * 576 + t];
    Gs[t] = s;
  }
  if (tid < 48) {
    const int r = (tid < 24) ? (h * 24 + tid) : (192 + h * 24 + tid - 24);
    float s = 0.f;
    #pragma unroll
    for (int j = 0; j < 8; j++) s += nrm2p[(size_t)r * 8 + j];
    float nv = fmaxf(sqrtf(s), 1e-12f);
    if (tid < 24) nq[tid] = nv; else nk[tid - 24] = nv;
  }
  __syncthreads();
  if (tid < 24) {
    const int d = tid;
    const float tp = temp[h];
    float row[24], mx = -1e30f;
    #pragma unroll
    for (int c = 0; c < 24; c++) {
      float v = Gs[d * 24 + c] * tp / (nq[d] * nk[c]);
      row[c] = v; mx = fmaxf(mx, v);
    }
    float s = 0.f;
    #pragma unroll
    for (int c = 0; c < 24; c++) { float e = expf(row[c] - mx); row[c] = e; s += e; }
    const float inv = 1.f / s;
    #pragma unroll
    for (int c = 0; c < 24; c++) P[h * 576 + d * 24 + c] = row[c] * inv;
  }
}

// ---- out_t[e][h*24+d] = sum_c P[h,d,c]*v[h,c,e]; grid (8, 64, 4) -----------
__global__ __launch_bounds__(256) void pv_kernel(
    const float* __restrict__ P, const __hip_bfloat16* __restrict__ qkv,
    __hip_bfloat16* __restrict__ yt) {
  const int b = blockIdx.z;
  P   += (size_t)b * 8 * 576;
  qkv += (size_t)b * 576 * HW_;
  yt  += (size_t)b * HW_ * 192;
  const int hh = blockIdx.x;
  const int e = blockIdx.y * 256 + threadIdx.x;
  __shared__ float Ps[576];
  for (int t = threadIdx.x; t < 576; t += 256) Ps[t] = P[hh * 576 + t];
  __syncthreads();
  const __hip_bfloat16* vb = qkv + (size_t)(384 + hh * 24) * HW_;
  float acc[24];
  #pragma unroll
  for (int d = 0; d < 24; d++) acc[d] = 0.f;
  for (int c = 0; c < 24; c++) {
    float v = (float)vb[(size_t)c * HW_ + e];
    #pragma unroll
    for (int d = 0; d < 24; d++) acc[d] += Ps[d * 24 + c] * v;
  }
  #pragma unroll
  for (int g = 0; g < 3; g++) {
    Pack8 pk;
    #pragma unroll
    for (int u = 0; u < 8; u++) pk.h[u] = __float2bfloat16(acc[g * 8 + u]);
    *(i32x4*)&yt[(size_t)e * 192 + hh * 24 + g * 8] = pk.v;
  }
}

// ---- FFN depthwise + GELU gate -> transposed gt[p][512], 4-row tiles -------
// grid (64 = yt*2+xh, 16 ch-groups, 2 batch-within-half). Block: 32 ch x
// 4 rows x 64 px. Rolling pass over 6 input rows. LDS 17KB -> ~8 blocks/CU.
__global__ __launch_bounds__(256) void dwg_t_kernel(
    const __hip_bfloat16* __restrict__ hsrc, const float* __restrict__ wdw,
    __hip_bfloat16* __restrict__ gt, int b0) {
  const int z = blockIdx.z;
  const int bb = b0 + z;
  const int yt = blockIdx.x >> 1, xh = blockIdx.x & 1;
  const int cz = blockIdx.y;
  const int tid = threadIdx.x;
  const int cl = tid >> 3, x8 = tid & 7;         // 32 ch x 8 px-groups
  const int c = cz * 32 + cl;
  const int y0 = yt * 4;
  const int pxb = xh * 64 + x8 * 8;              // global px base
  __shared__ __hip_bfloat16 sg[32][266];         // [ch][4*64] pad->266

  const bool active = (c < 510);
  const int ca = active ? c : 0;
  const __hip_bfloat16* ha = hsrc + ((size_t)bb * 1024 + ca) * HW_;
  const __hip_bfloat16* hb = hsrc + ((size_t)bb * 1024 + ca + 510) * HW_;
  float wva[9], wvb[9];
  #pragma unroll
  for (int u = 0; u < 9; u++) {
    wva[u] = active ? wdw[c * 9 + u] : 0.f;
    wvb[u] = active ? wdw[(c + 510) * 9 + u] : 0.f;
  }

  float aA[3][8], aB[3][8];
  #pragma unroll
  for (int s = 0; s < 3; s++)
    #pragma unroll
    for (int j = 0; j < 8; j++) { aA[s][j] = 0.f; aB[s][j] = 0.f; }

  #pragma unroll
  for (int i = 0; i < 6; i++) {
    const int ry = y0 - 1 + i;
    float ra[10], rb[10];
    if (ry >= 0 && ry < 128) {
      const int off = ry * 128 + pxb;
      Pack8 ma; ma.v = *(const i32x4*)(ha + off);
      Pack8 mb; mb.v = *(const i32x4*)(hb + off);
      ra[0] = (pxb > 0) ? (float)ha[off - 1] : 0.f;
      rb[0] = (pxb > 0) ? (float)hb[off - 1] : 0.f;
      #pragma unroll
      for (int u = 0; u < 8; u++) { ra[1 + u] = (float)ma.h[u]; rb[1 + u] = (float)mb.h[u]; }
      ra[9] = (pxb < 120) ? (float)ha[off + 8] : 0.f;
      rb[9] = (pxb < 120) ? (float)hb[off + 8] : 0.f;
    } else {
      #pragma unroll
      for (int u = 0; u < 10; u++) { ra[u] = 0.f; rb[u] = 0.f; }
    }
    // input row ry feeds output rows lo = i-r (weight-row r)
    #pragma unroll
    for (int r = 0; r < 3; r++) {
      const int lo = i - r;
      if (lo < 0 || lo >= 4) continue;
      const int s = lo % 3;
      const float a0 = wva[r * 3], a1 = wva[r * 3 + 1], a2 = wva[r * 3 + 2];
      const float b0w = wvb[r * 3], b1 = wvb[r * 3 + 1], b2 = wvb[r * 3 + 2];
      #pragma unroll
      for (int j = 0; j < 8; j++) {
        aA[s][j] += a0 * ra[j] + a1 * ra[j + 1] + a2 * ra[j + 2];
        aB[s][j] += b0w * rb[j] + b1 * rb[j + 1] + b2 * rb[j + 2];
      }
    }
    // output row lo = i-2 is complete: gate + stage to LDS, recycle slot
    {
      const int lo = i - 2;
      if (lo >= 0 && lo < 4) {
        const int s = lo % 3;
        Pack8 o;
        #pragma unroll
        for (int j = 0; j < 8; j++) {
          float v = aA[s][j];
          float ge = 0.5f * v * (1.f + erff(v * 0.70710678118654752f));
          o.h[j] = __float2bfloat16(ge * aB[s][j]);
          aA[s][j] = 0.f; aB[s][j] = 0.f;
        }
        *(i32x4*)&sg[cl][lo * 64 + x8 * 8] = o.v;
      }
    }
  }
  __syncthreads();
  // transposed write: 256 local px x 32 ch; 4 lanes cover one 64B px segment
  const int sp = tid >> 2, ch0 = (tid & 3) * 8;
  #pragma unroll
  for (int k = 0; k < 4; k++) {
    Pack8 o;
    #pragma unroll
    for (int u = 0; u < 8; u++) o.h[u] = sg[ch0 + u][k * 64 + sp];
    const int gp = (y0 + k) * 128 + xh * 64 + sp;
    *(i32x4*)&gt[((size_t)z * HW_ + gp) * 512 + cz * 32 + ch0] = o.v;
  }
}

// ---------------------------------------------------------------------------
extern "C" void kernel_launch(void* const* d_in, const int* in_sizes, int n_in,
                              void* d_out, int out_size, void* d_ws, size_t ws_size,
                              hipStream_t stream) {
  const float* x     = (const float*)d_in[0];
  const float* temp  = (const float*)d_in[1];
  const float* ln1w  = (const float*)d_in[2];
  const float* ln1b  = (const float*)d_in[3];
  const float* ln2w  = (const float*)d_in[4];
  const float* ln2b  = (const float*)d_in[5];
  const float* wqkv  = (const float*)d_in[6];
  const float* wqkvdw= (const float*)d_in[7];
  const float* wproj = (const float*)d_in[8];
  const float* win   = (const float*)d_in[9];
  const float* wdw   = (const float*)d_in[10];
  const float* wout  = (const float*)d_in[11];
  float* out = (float*)d_out;
  char* ws = (char*)d_ws;

  const int HW = 16384;
  const size_t HWC = (size_t)192 * HW;

  __hip_bfloat16* yt    = (__hip_bfloat16*)(ws + 0);
  __hip_bfloat16* qkva  = (__hip_bfloat16*)(ws + 25165824);
  __hip_bfloat16* qkvb  = (__hip_bfloat16*)(ws + 100663296);
  __hip_bfloat16* hbuf  = (__hip_bfloat16*)(ws + 25165824);   // aliases dead qkva/qkvb
  float*          xa    = (float*)(ws + 176160768);
  __hip_bfloat16* gt    = (__hip_bfloat16*)(ws + 226492416);  // 2 half-batches
  __hip_bfloat16* wqkvB = (__hip_bfloat16*)(ws + 260046848);
  __hip_bfloat16* wprojB= (__hip_bfloat16*)(ws + 260268032);
  __hip_bfloat16* winB  = (__hip_bfloat16*)(ws + 260341760);
  __hip_bfloat16* woutB = (__hip_bfloat16*)(ws + 260734976);
  float*          nrm2p = (float*)(ws + 260931584);
  float*          Gpart = (float*)(ws + 260980736);
  float*          P     = (float*)(ws + 263340032);

  convert_weights<<<768, 256, 0, stream>>>(wqkv, wproj, win, wout,
                                           wqkvB, wprojB, winB, woutB);

  // 1. yt = LN1(x), all batches
  ln_t_kernel<<<dim3(256, 4), 256, 0, stream>>>(x, ln1w, ln1b, yt);
  // 2. qkva = w_qkv @ y   (576 x 16384) x4 — B-stationary, 64-col panels
  gemm_bstat<0><<<dim3(256, 4), 256, 0, stream>>>(
      wqkvB, yt, nullptr, qkva, 9, (size_t)HW * 192, 0, (size_t)576 * HW);
  // 3. qkvb = dwconv3x3(qkva) + nrm2 partials
  dw_kernel<<<dim3(8, 576, 4), 256, 0, stream>>>(qkva, wqkvdw, qkvb, nrm2p);
  // 4. Gram partials via MFMA
  gram_kernel<<<dim3(8, 32, 4), 256, 0, stream>>>(qkvb, Gpart);
  // 5. P = softmax(reduce(Gpart) * temp / (|q||k|))
  softmax2_kernel<<<dim3(8, 4), 256, 0, stream>>>(Gpart, nrm2p, temp, P);
  // 6. yt = (P @ v)^T bf16
  pv_kernel<<<dim3(8, 64, 4), 256, 0, stream>>>(P, qkvb, yt);
  // 7. xa = x + w_proj @ pv — B-stationary with residual epilogue
  gemm_bstat<1><<<dim3(256, 4), 256, 0, stream>>>(
      wprojB, yt, x, xa, 3, (size_t)HW * 192, HWC, HWC);
  // 8. yt = LN2(xa)
  ln_t_kernel<<<dim3(256, 4), 256, 0, stream>>>(xa, ln2w, ln2b, yt);
  // 9. hbuf = w_in @ y   (1024 x 16384) x4 — B-stationary (rows>=1020 zero)
  gemm_bstat<0><<<dim3(256, 4), 256, 0, stream>>>(
      winB, yt, nullptr, hbuf, 16, (size_t)HW * 192, 0, (size_t)1024 * HW);
  // 10-13. FFN tail in two half-batches: gate(+transpose) then w_out GEMM
  for (int half = 0; half < 2; half++) {
    const int b0 = half * 2;
    dwg_t_kernel<<<dim3(64, 16, 2), 256, 0, stream>>>(hbuf, wdw, gt, b0);
    mfma_gemm<1><<<dim3(3, 128, 2), 256, 0, stream>>>(
        woutB, gt, xa + (size_t)b0 * HWC, out + (size_t)b0 * HWC,
        192, HW, 512, (size_t)HW * 512, HWC, HWC);
  }
}

// Round 8
// 471.242 us; speedup vs baseline: 1.0800x; 1.0124x over previous
//
#include <hip/hip_runtime.h>
#include <hip/hip_bf16.h>
#include <math.h>

// ---------------------------------------------------------------------------
// Round 15 = r14 base + branchless/hoistable loads in dwg_t and dw_kernel.
// r14 showed dwg_t at 68 µs, latency-bound (occ 28%, VALU 22%, MFMA 0,
// hbm 1.9 TB/s): each row's loads sat inside `if (ry valid)` branches, so
// the 6 row loads issued serially (6 latency round-trips/thread). v3 clamps
// the row index (always-legal address), zeroes via a {0,1} multiplier, and
// pulls left/right halos from __shfl (edge lanes: tiny branched scalar
// loads). All 12 dwordx4 loads now issue back-to-back. Same treatment for
// dw_kernel's 3 rows. GEMMs unchanged from r14 (64-col B-stationary).
//
// ws layout (bytes):
//   yt4    @ 0            25,165,824  bf16 [b][p][192]
//   qkva4  @ 25,165,824   75,497,472  bf16 [b][576][p]
//   qkvb4  @ 100,663,296  75,497,472  bf16 [b][576][p]
//   hbuf4  @ 25,165,824  134,217,728  bf16 [b][1024][p]  (aliases dead qkva/qkvb)
//   xa4    @ 176,160,768  50,331,648  fp32 [b][192][p]
//   gt2    @ 226,492,416  33,554,432  bf16 [z][p][512]   (half-batch)
//   wqkvB  @ 260,046,848     221,184
//   wprojB @ 260,268,032      73,728
//   winB   @ 260,341,760     393,216  (1024x192, rows >=1020 zero)
//   woutB  @ 260,734,976     196,608  (192x512, cols >=510 zero)
//   nrm2p  @ 260,931,584      49,152  fp32 [b][384][8]
//   Gpart  @ 260,980,736   2,359,296  fp32 [b][32][8][576]
//   P      @ 263,340,032      73,728  fp32 [b][8][576]
// total 263,413,760 <= 268,435,456. No atomics, no memsets.
// ---------------------------------------------------------------------------

#define HW_ 16384

typedef __attribute__((ext_vector_type(8))) short bf16x8;
typedef __attribute__((ext_vector_type(4))) float f32x4;
typedef __attribute__((ext_vector_type(16))) float f32x16;
typedef __attribute__((ext_vector_type(4))) int i32x4;

union Pack8 { __hip_bfloat16 h[8]; i32x4 v; };

// ---- weight fp32 -> bf16 conversion (with padding) -------------------------
__global__ __launch_bounds__(256) void convert_weights(
    const float* __restrict__ wqkv, const float* __restrict__ wproj,
    const float* __restrict__ win, const float* __restrict__ wout,
    __hip_bfloat16* __restrict__ oq, __hip_bfloat16* __restrict__ op,
    __hip_bfloat16* __restrict__ oi, __hip_bfloat16* __restrict__ oo) {
  const int i = blockIdx.x * 256 + threadIdx.x;
  if (i < 110592) oq[i] = __float2bfloat16(wqkv[i]);            // 576x192
  if (i < 36864)  op[i] = __float2bfloat16(wproj[i]);           // 192x192
  if (i < 196608) {                                             // 1024x192 pad
    int m = i / 192, k = i - m * 192;
    oi[i] = __float2bfloat16(m < 1020 ? win[m * 192 + k] : 0.f);
  }
  if (i < 98304) {                                              // 192x512 pad
    int m = i >> 9, k = i & 511;
    oo[i] = __float2bfloat16(k < 510 ? wout[m * 510 + k] : 0.f);
  }
}

// ---- channel LN -> transposed bf16 output [p][192]; grid (256, batch) ------
__global__ __launch_bounds__(256) void ln_t_kernel(
    const float* __restrict__ x, const float* __restrict__ w,
    const float* __restrict__ bi, __hip_bfloat16* __restrict__ yt) {
  const int b = blockIdx.y;
  x += (size_t)b * 192 * HW_;
  yt += (size_t)b * HW_ * 192;
  __shared__ float tile[192][68];
  __shared__ float psum[4][64], psq[4][64];
  __shared__ float mu_s[64], inv_s[64];
  const int tid = threadIdx.x;
  const int p0 = blockIdx.x * 64;
  for (int idx = tid; idx < 192 * 16; idx += 256) {
    int c = idx >> 4, p4 = idx & 15;
    f32x4 v = *(const f32x4*)(x + (size_t)c * HW_ + p0 + p4 * 4);
    *(f32x4*)&tile[c][p4 * 4] = v;
  }
  __syncthreads();
  const int tx = tid & 63, ty = tid >> 6;
  float s = 0.f, s2 = 0.f;
  for (int c = ty * 48; c < ty * 48 + 48; c++) {
    float v = tile[c][tx]; s += v; s2 += v * v;
  }
  psum[ty][tx] = s; psq[ty][tx] = s2;
  __syncthreads();
  if (ty == 0) {
    float ts = psum[0][tx] + psum[1][tx] + psum[2][tx] + psum[3][tx];
    float ts2 = psq[0][tx] + psq[1][tx] + psq[2][tx] + psq[3][tx];
    float mu = ts * (1.f / 192.f);
    float var = ts2 * (1.f / 192.f) - mu * mu;
    mu_s[tx] = mu; inv_s[tx] = rsqrtf(var + 1e-5f);
  }
  __syncthreads();
  for (int idx = tid; idx < 64 * 24; idx += 256) {
    int c8 = idx % 24, p = idx / 24;
    float mu = mu_s[p], inv = inv_s[p];
    Pack8 pk;
    #pragma unroll
    for (int u = 0; u < 8; u++) {
      int c = c8 * 8 + u;
      pk.h[u] = __float2bfloat16((tile[c][p] - mu) * inv * w[c] + bi[c]);
    }
    *(i32x4*)&yt[(size_t)(p0 + p) * 192 + c8 * 8] = pk.v;
  }
}

// ---- B-stationary MFMA GEMM, 64-col panels: D[M][HW] = A[M][192]@B[HW][192]^T
// grid (HW/64, batch). B panel (64x192) in LDS once; M-loop with A
// reg-prefetch + LDS staging (r8/r12-proven 2-barrier structure).
// XOR-swizzled LDS, conflict-free b128. EPI=0: bf16 out. EPI=1: fp32 + res C.
template <int EPI>
__global__ __launch_bounds__(256) void gemm_bstat(
    const __hip_bfloat16* __restrict__ A, const __hip_bfloat16* __restrict__ Bg,
    const float* __restrict__ Cres, void* __restrict__ Dout,
    int Mtiles, size_t Bstr, size_t Cstr, size_t Dstr) {
  const int z = blockIdx.y;
  const __hip_bfloat16* B = Bg + (size_t)z * Bstr;
  const int col0 = blockIdx.x * 64;
  __shared__ __align__(16) __hip_bfloat16 Bs[64][192];
  __shared__ __align__(16) __hip_bfloat16 As[64][192];
  const int tid = threadIdx.x;
  const int wave = tid >> 6, lane = tid & 63;
  const int quad = lane >> 4, lr = lane & 15;
  const int wm = (wave & 1) * 32, wn = (wave >> 1) * 32;
  const int lrx = lr & 7;                      // read-side XOR (row&7 == lrx)

  const int arow = tid >> 3, ach = tid & 7;    // staging coords (32 rows x 8 ch)
  const int achs = ach ^ (arow & 7);           // swizzled chunk base

  // --- load B panel (once), swizzled ---
  #pragma unroll
  for (int l = 0; l < 2; l++) {
    const int row = arow + 32 * l;
    const __hip_bfloat16* bp = B + (size_t)(col0 + row) * 192;
    #pragma unroll
    for (int j = 0; j < 3; j++) {
      i32x4 v = *(const i32x4*)(bp + (ach + 8 * j) * 8);
      *(i32x4*)&Bs[row][(achs + 8 * j) * 8] = v;
    }
  }
  // --- prefetch A tile 0 to regs ---
  i32x4 areg[6];
  #pragma unroll
  for (int l = 0; l < 2; l++)
    #pragma unroll
    for (int j = 0; j < 3; j++)
      areg[l * 3 + j] = *(const i32x4*)(
          A + (size_t)(arow + 32 * l) * 192 + (ach + 8 * j) * 8);
  // --- stage A tile 0 ---
  #pragma unroll
  for (int l = 0; l < 2; l++)
    #pragma unroll
    for (int j = 0; j < 3; j++)
      *(i32x4*)&As[arow + 32 * l][(achs + 8 * j) * 8] = areg[l * 3 + j];
  __syncthreads();

  for (int mt = 0; mt < Mtiles; mt++) {
    const int row0 = mt * 64;
    if (mt + 1 < Mtiles) {                     // issue next A loads (L2-hit)
      const __hip_bfloat16* ap = A + (size_t)(mt + 1) * 64 * 192;
      #pragma unroll
      for (int l = 0; l < 2; l++)
        #pragma unroll
        for (int j = 0; j < 3; j++)
          areg[l * 3 + j] = *(const i32x4*)(
              ap + (size_t)(arow + 32 * l) * 192 + (ach + 8 * j) * 8);
    }
    f32x4 acc[2][2];
    #pragma unroll
    for (int i = 0; i < 2; i++)
      #pragma unroll
      for (int j = 0; j < 2; j++) acc[i][j] = (f32x4){0.f, 0.f, 0.f, 0.f};
    #pragma unroll
    for (int kc = 0; kc < 6; kc++) {
      const int chq = ((kc * 4 + quad) ^ lrx) * 8;
      bf16x8 a0 = *(const bf16x8*)&As[wm + lr][chq];
      bf16x8 a1 = *(const bf16x8*)&As[wm + 16 + lr][chq];
      #pragma unroll
      for (int j = 0; j < 2; j++) {
        bf16x8 bb = *(const bf16x8*)&Bs[wn + j * 16 + lr][chq];
        acc[0][j] = __builtin_amdgcn_mfma_f32_16x16x32_bf16(a0, bb, acc[0][j], 0, 0, 0);
        acc[1][j] = __builtin_amdgcn_mfma_f32_16x16x32_bf16(a1, bb, acc[1][j], 0, 0, 0);
      }
    }
    #pragma unroll
    for (int i = 0; i < 2; i++)
      #pragma unroll
      for (int r = 0; r < 4; r++) {
        const int gm = row0 + wm + i * 16 + quad * 4 + r;
        const size_t base = (size_t)gm * HW_ + col0 + wn + lr;
        if (EPI == 0) {
          __hip_bfloat16* dp = (__hip_bfloat16*)Dout + (size_t)z * Dstr + base;
          #pragma unroll
          for (int j = 0; j < 2; j++) dp[j * 16] = __float2bfloat16(acc[i][j][r]);
        } else {
          float* dp = (float*)Dout + (size_t)z * Dstr + base;
          const float* cp = Cres + (size_t)z * Cstr + base;
          #pragma unroll
          for (int j = 0; j < 2; j++) dp[j * 16] = acc[i][j][r] + cp[j * 16];
        }
      }
    __syncthreads();                           // all waves done reading As
    if (mt + 1 < Mtiles) {
      #pragma unroll
      for (int l = 0; l < 2; l++)
        #pragma unroll
        for (int j = 0; j < 3; j++)
          *(i32x4*)&As[arow + 32 * l][(achs + 8 * j) * 8] = areg[l * 3 + j];
      __syncthreads();
    }
  }
}

// ---- MFMA GEMM: D[M][N] = A[M][K] @ B_t[N][K]^T (+res); z = batch ----------
// (kept for w_out; XOR-swizzled LDS, no pad)
template <int EPI>
__global__ __launch_bounds__(256) void mfma_gemm(
    const __hip_bfloat16* __restrict__ A, const __hip_bfloat16* __restrict__ Bg,
    const float* __restrict__ Cres, void* __restrict__ Dout,
    int M, int N, int K, size_t Bstr, size_t Cstr, size_t Dstr) {
  const int z = blockIdx.z;
  const __hip_bfloat16* B = Bg + (size_t)z * Bstr;
  const float* C = Cres ? Cres + (size_t)z * Cstr : nullptr;
  __shared__ __align__(16) __hip_bfloat16 As[64][64];
  __shared__ __align__(16) __hip_bfloat16 Bs[128][64];
  const int tid = threadIdx.x;
  const int wave = tid >> 6, lane = tid & 63;
  const int quad = lane >> 4, lr = lane & 15;
  const int lrx = lr & 7;
  const int wm = (wave & 1) * 32, wn = (wave >> 1) * 64;
  const int row0 = blockIdx.x * 64, col0 = blockIdx.y * 128;

  f32x4 acc[2][4];
  #pragma unroll
  for (int i = 0; i < 2; i++)
    #pragma unroll
    for (int j = 0; j < 4; j++) acc[i][j] = (f32x4){0.f, 0.f, 0.f, 0.f};

  for (int k0 = 0; k0 < K; k0 += 64) {
    #pragma unroll
    for (int l = 0; l < 2; l++) {
      int t = tid + l * 256;
      int row = t >> 3, ch = t & 7;
      i32x4 v = *(const i32x4*)(A + (size_t)(row0 + row) * K + k0 + ch * 8);
      *(i32x4*)&As[row][(ch ^ (row & 7)) * 8] = v;
    }
    #pragma unroll
    for (int l = 0; l < 4; l++) {
      int t = tid + l * 256;
      int row = t >> 3, ch = t & 7;
      i32x4 v = *(const i32x4*)(B + (size_t)(col0 + row) * K + k0 + ch * 8);
      *(i32x4*)&Bs[row][(ch ^ (row & 7)) * 8] = v;
    }
    __syncthreads();
    #pragma unroll
    for (int ks = 0; ks < 2; ks++) {
      const int chq = ((ks * 4 + quad) ^ lrx) * 8;
      bf16x8 a0 = *(const bf16x8*)&As[wm + lr][chq];
      bf16x8 a1 = *(const bf16x8*)&As[wm + 16 + lr][chq];
      #pragma unroll
      for (int j = 0; j < 4; j++) {
        bf16x8 bb = *(const bf16x8*)&Bs[wn + j * 16 + lr][chq];
        acc[0][j] = __builtin_amdgcn_mfma_f32_16x16x32_bf16(a0, bb, acc[0][j], 0, 0, 0);
        acc[1][j] = __builtin_amdgcn_mfma_f32_16x16x32_bf16(a1, bb, acc[1][j], 0, 0, 0);
      }
    }
    __syncthreads();
  }

  #pragma unroll
  for (int i = 0; i < 2; i++) {
    #pragma unroll
    for (int r = 0; r < 4; r++) {
      int gm = row0 + wm + i * 16 + quad * 4 + r;
      if (gm >= M) continue;
      #pragma unroll
      for (int j = 0; j < 4; j++) {
        int gn = col0 + wn + j * 16 + lr;
        size_t idx = (size_t)gm * N + gn;
        if (EPI == 0) {
          (((__hip_bfloat16*)Dout) + (size_t)z * Dstr)[idx] = __float2bfloat16(acc[i][j][r]);
        } else {
          (((float*)Dout) + (size_t)z * Dstr)[idx] = acc[i][j][r] + C[idx];
        }
      }
    }
  }
}

// ---- depthwise 3x3 (8 px/thread) + fused q,k sum-of-squares partials -------
// branchless clamped row loads (hoistable) + shfl halos
__global__ __launch_bounds__(256) void dw_kernel(
    const __hip_bfloat16* __restrict__ in, const float* __restrict__ wdw,
    __hip_bfloat16* __restrict__ out, float* __restrict__ nrm2p) {
  const int b = blockIdx.z;
  in  += (size_t)b * 576 * HW_;
  out += (size_t)b * 576 * HW_;
  const int c = blockIdx.y;
  const int x8 = threadIdx.x & 15;
  const int y = blockIdx.x * 16 + (threadIdx.x >> 4);
  const __hip_bfloat16* ip = in + (size_t)c * HW_;
  const float* wp = wdw + c * 9;
  float wv[9];
  #pragma unroll
  for (int u = 0; u < 9; u++) wv[u] = wp[u];
  // phase 1: all 3 row loads, clamped addresses (unconditional -> hoisted)
  i32x4 vrow[3]; float vf[3];
  #pragma unroll
  for (int r = 0; r < 3; r++) {
    const int yy = y + r - 1;
    const int yyc = yy < 0 ? 0 : (yy > 127 ? 127 : yy);
    vf[r] = (yy >= 0 && yy < 128) ? 1.f : 0.f;
    vrow[r] = *(const i32x4*)(ip + yyc * 128 + x8 * 8);
  }
  float acc[8];
  #pragma unroll
  for (int j = 0; j < 8; j++) acc[j] = 0.f;
  #pragma unroll
  for (int r = 0; r < 3; r++) {
    Pack8 mid; mid.v = vrow[r];
    const int hi = vrow[r][3];
    const int lo = vrow[r][0];
    const int lw = __shfl_up(hi, 1, 64);
    const int rw = __shfl_down(lo, 1, 64);
    float row[10];
    row[0] = (x8 > 0) ? vf[r] * (float)(((const __hip_bfloat16*)&lw)[1]) : 0.f;
    #pragma unroll
    for (int u = 0; u < 8; u++) row[1 + u] = vf[r] * (float)mid.h[u];
    row[9] = (x8 < 15) ? vf[r] * (float)(((const __hip_bfloat16*)&rw)[0]) : 0.f;
    const float wl = wv[r * 3], wc = wv[r * 3 + 1], wr = wv[r * 3 + 2];
    #pragma unroll
    for (int j = 0; j < 8; j++)
      acc[j] += wl * row[j] + wc * row[j + 1] + wr * row[j + 2];
  }
  Pack8 o;
  #pragma unroll
  for (int j = 0; j < 8; j++) o.h[j] = __float2bfloat16(acc[j]);
  *(i32x4*)(out + (size_t)c * HW_ + y * 128 + x8 * 8) = o.v;
  if (c < 384) {
    float s = 0.f;
    #pragma unroll
    for (int j = 0; j < 8; j++) s += acc[j] * acc[j];
    #pragma unroll
    for (int off = 32; off > 0; off >>= 1) s += __shfl_down(s, off, 64);
    __shared__ float wsum[4];
    const int lane = threadIdx.x & 63, wvi = threadIdx.x >> 6;
    if (lane == 0) wsum[wvi] = s;
    __syncthreads();
    if (threadIdx.x == 0)
      nrm2p[((size_t)b * 384 + c) * 8 + blockIdx.x] =
          wsum[0] + wsum[1] + wsum[2] + wsum[3];
  }
}

// ---- MFMA Gram partials; grid (8 heads, 32 chunks, 4 batch) ----------------
__global__ __launch_bounds__(256) void gram_kernel(
    const __hip_bfloat16* __restrict__ qkv, float* __restrict__ Gpart) {
  const int b = blockIdx.z;
  qkv   += (size_t)b * 576 * HW_;
  Gpart += (size_t)b * 32 * 8 * 576;
  const int h = blockIdx.x, chunk = blockIdx.y;
  const int tid = threadIdx.x;
  const int w = tid >> 6, lane = tid & 63;
  const int m = lane & 31;
  const int khalf = lane >> 5;
  const __hip_bfloat16* qb = qkv + (size_t)(h * 24) * HW_;
  const __hip_bfloat16* kb = qkv + (size_t)(192 + h * 24) * HW_;
  f32x16 acc;
  #pragma unroll
  for (int i = 0; i < 16; i++) acc[i] = 0.f;
  const int e0 = chunk * 512 + w * 128;
  #pragma unroll
  for (int j = 0; j < 8; j++) {
    const int k0 = e0 + j * 16 + khalf * 8;
    bf16x8 a = *(const bf16x8*)(qb + (size_t)m * HW_ + k0);
    bf16x8 bfr = *(const bf16x8*)(kb + (size_t)m * HW_ + k0);
    acc = __builtin_amdgcn_mfma_f32_32x32x16_bf16(a, bfr, acc, 0, 0, 0);
  }
  __shared__ float gs[4][576];
  #pragma unroll
  for (int r = 0; r < 16; r++) {
    int row = (r & 3) + 8 * (r >> 2) + 4 * khalf;
    if (row < 24 && m < 24) gs[w][row * 24 + m] = acc[r];
  }
  __syncthreads();
  float* gp = Gpart + (size_t)(chunk * 8 + h) * 576;
  for (int t = tid; t < 576; t += 256)
    gp[t] = gs[0][t] + gs[1][t] + gs[2][t] + gs[3][t];
}

// ---- reduce Gpart + nrm2p partials, softmax -> P; grid (8 heads, 4 batch) --
__global__ __launch_bounds__(256) void softmax2_kernel(
    const float* __restrict__ Gpart, const float* __restrict__ nrm2p,
    const float* __restrict__ temp, float* __restrict__ P) {
  const int b = blockIdx.y;
  Gpart += (size_t)b * 32 * 8 * 576;
  nrm2p += (size_t)b * 384 * 8;
  P     += (size_t)b * 8 * 576;
  const int h = blockIdx.x;
  const int tid = threadIdx.x;
  __shared__ float Gs[576];
  __shared__ float nq[24], nk[24];
  for (int t = tid; t < 576; t += 256) {
    float s = 0.f;
    for (int ch = 0; ch < 32; ch++)
      s += Gpart[(size_t)(ch * 8 + h) * 576 + t];
    Gs[t] = s;
  }
  if (tid < 48) {
    const int r = (tid < 24) ? (h * 24 + tid) : (192 + h * 24 + tid - 24);
    float s = 0.f;
    #pragma unroll
    for (int j = 0; j < 8; j++) s += nrm2p[(size_t)r * 8 + j];
    float nv = fmaxf(sqrtf(s), 1e-12f);
    if (tid < 24) nq[tid] = nv; else nk[tid - 24] = nv;
  }
  __syncthreads();
  if (tid < 24) {
    const int d = tid;
    const float tp = temp[h];
    float row[24], mx = -1e30f;
    #pragma unroll
    for (int c = 0; c < 24; c++) {
      float v = Gs[d * 24 + c] * tp / (nq[d] * nk[c]);
      row[c] = v; mx = fmaxf(mx, v);
    }
    float s = 0.f;
    #pragma unroll
    for (int c = 0; c < 24; c++) { float e = expf(row[c] - mx); row[c] = e; s += e; }
    const float inv = 1.f / s;
    #pragma unroll
    for (int c = 0; c < 24; c++) P[h * 576 + d * 24 + c] = row[c] * inv;
  }
}

// ---- out_t[e][h*24+d] = sum_c P[h,d,c]*v[h,c,e]; grid (8, 64, 4) -----------
__global__ __launch_bounds__(256) void pv_kernel(
    const float* __restrict__ P, const __hip_bfloat16* __restrict__ qkv,
    __hip_bfloat16* __restrict__ yt) {
  const int b = blockIdx.z;
  P   += (size_t)b * 8 * 576;
  qkv += (size_t)b * 576 * HW_;
  yt  += (size_t)b * HW_ * 192;
  const int hh = blockIdx.x;
  const int e = blockIdx.y * 256 + threadIdx.x;
  __shared__ float Ps[576];
  for (int t = threadIdx.x; t < 576; t += 256) Ps[t] = P[hh * 576 + t];
  __syncthreads();
  const __hip_bfloat16* vb = qkv + (size_t)(384 + hh * 24) * HW_;
  float acc[24];
  #pragma unroll
  for (int d = 0; d < 24; d++) acc[d] = 0.f;
  for (int c = 0; c < 24; c++) {
    float v = (float)vb[(size_t)c * HW_ + e];
    #pragma unroll
    for (int d = 0; d < 24; d++) acc[d] += Ps[d * 24 + c] * v;
  }
  #pragma unroll
  for (int g = 0; g < 3; g++) {
    Pack8 pk;
    #pragma unroll
    for (int u = 0; u < 8; u++) pk.h[u] = __float2bfloat16(acc[g * 8 + u]);
    *(i32x4*)&yt[(size_t)e * 192 + hh * 24 + g * 8] = pk.v;
  }
}

// ---- FFN depthwise + GELU gate -> transposed gt[p][512], 4-row tiles -------
// v3: branchless clamped row loads (all 12 dwordx4 issue upfront), shfl
// halos, edge lanes via 2 small branches. grid (64, 16, 2).
__global__ __launch_bounds__(256) void dwg_t_kernel(
    const __hip_bfloat16* __restrict__ hsrc, const float* __restrict__ wdw,
    __hip_bfloat16* __restrict__ gt, int b0) {
  const int z = blockIdx.z;
  const int bb = b0 + z;
  const int yt = blockIdx.x >> 1, xh = blockIdx.x & 1;
  const int cz = blockIdx.y;
  const int tid = threadIdx.x;
  const int cl = tid >> 3, x8 = tid & 7;         // 32 ch x 8 px-groups
  const int c = cz * 32 + cl;
  const int y0 = yt * 4;
  const int pxb = xh * 64 + x8 * 8;              // global px base
  __shared__ __hip_bfloat16 sg[32][266];         // [ch][4*64] pad->266

  const bool active = (c < 510);
  const int ca = active ? c : 0;
  const __hip_bfloat16* ha = hsrc + ((size_t)bb * 1024 + ca) * HW_;
  const __hip_bfloat16* hb = hsrc + ((size_t)bb * 1024 + ca + 510) * HW_;
  float wva[9], wvb[9];
  #pragma unroll
  for (int u = 0; u < 9; u++) {
    wva[u] = active ? wdw[c * 9 + u] : 0.f;
    wvb[u] = active ? wdw[(c + 510) * 9 + u] : 0.f;
  }

  // phase 1: all 6 row-pair loads with clamped row index (unconditional)
  i32x4 va[6], vbv[6];
  float vf[6];
  int offr[6];
  #pragma unroll
  for (int i = 0; i < 6; i++) {
    const int ry = y0 - 1 + i;
    const int ryc = ry < 0 ? 0 : (ry > 127 ? 127 : ry);
    vf[i] = (ry >= 0 && ry < 128) ? 1.f : 0.f;
    offr[i] = ryc * 128 + pxb;
    va[i]  = *(const i32x4*)(ha + offr[i]);
    vbv[i] = *(const i32x4*)(hb + offr[i]);
  }
  // phase 2: edge halos (only the block-boundary lanes need real loads)
  float leA[6], leB[6], reA[6], reB[6];
  #pragma unroll
  for (int i = 0; i < 6; i++) { leA[i] = 0.f; leB[i] = 0.f; reA[i] = 0.f; reB[i] = 0.f; }
  if (x8 == 0 && xh == 1) {
    #pragma unroll
    for (int i = 0; i < 6; i++) {
      leA[i] = vf[i] * (float)ha[offr[i] - 1];
      leB[i] = vf[i] * (float)hb[offr[i] - 1];
    }
  }
  if (x8 == 7 && xh == 0) {
    #pragma unroll
    for (int i = 0; i < 6; i++) {
      reA[i] = vf[i] * (float)ha[offr[i] + 8];
      reB[i] = vf[i] * (float)hb[offr[i] + 8];
    }
  }

  float aA[3][8], aB[3][8];
  #pragma unroll
  for (int s = 0; s < 3; s++)
    #pragma unroll
    for (int j = 0; j < 8; j++) { aA[s][j] = 0.f; aB[s][j] = 0.f; }

  #pragma unroll
  for (int i = 0; i < 6; i++) {
    const int hiA = va[i][3],  loA = va[i][0];
    const int hiB = vbv[i][3], loB = vbv[i][0];
    const int lwA = __shfl_up(hiA, 1, 64), rwA = __shfl_down(loA, 1, 64);
    const int lwB = __shfl_up(hiB, 1, 64), rwB = __shfl_down(loB, 1, 64);
    Pack8 ma; ma.v = va[i];
    Pack8 mb; mb.v = vbv[i];
    float ra[10], rb[10];
    ra[0] = (x8 > 0) ? vf[i] * (float)(((const __hip_bfloat16*)&lwA)[1]) : leA[i];
    rb[0] = (x8 > 0) ? vf[i] * (float)(((const __hip_bfloat16*)&lwB)[1]) : leB[i];
    #pragma unroll
    for (int u = 0; u < 8; u++) {
      ra[1 + u] = vf[i] * (float)ma.h[u];
      rb[1 + u] = vf[i] * (float)mb.h[u];
    }
    ra[9] = (x8 < 7) ? vf[i] * (float)(((const __hip_bfloat16*)&rwA)[0]) : reA[i];
    rb[9] = (x8 < 7) ? vf[i] * (float)(((const __hip_bfloat16*)&rwB)[0]) : reB[i];
    // input row feeds output rows lo = i-r (weight-row r)
    #pragma unroll
    for (int r = 0; r < 3; r++) {
      const int lo = i - r;
      if (lo < 0 || lo >= 4) continue;
      const int s = lo % 3;
      const float a0 = wva[r * 3], a1 = wva[r * 3 + 1], a2 = wva[r * 3 + 2];
      const float b0w = wvb[r * 3], b1 = wvb[r * 3 + 1], b2 = wvb[r * 3 + 2];
      #pragma unroll
      for (int j = 0; j < 8; j++) {
        aA[s][j] += a0 * ra[j] + a1 * ra[j + 1] + a2 * ra[j + 2];
        aB[s][j] += b0w * rb[j] + b1 * rb[j + 1] + b2 * rb[j + 2];
      }
    }
    // output row lo = i-2 complete: gate + stage to LDS, recycle slot
    {
      const int lo = i - 2;
      if (lo >= 0 && lo < 4) {
        const int s = lo % 3;
        Pack8 o;
        #pragma unroll
        for (int j = 0; j < 8; j++) {
          float v = aA[s][j];
          float ge = 0.5f * v * (1.f + erff(v * 0.70710678118654752f));
          o.h[j] = __float2bfloat16(ge * aB[s][j]);
          aA[s][j] = 0.f; aB[s][j] = 0.f;
        }
        *(i32x4*)&sg[cl][lo * 64 + x8 * 8] = o.v;
      }
    }
  }
  __syncthreads();
  // transposed write: 256 local px x 32 ch; 4 lanes cover one 64B px segment
  const int sp = tid >> 2, ch0 = (tid & 3) * 8;
  #pragma unroll
  for (int k = 0; k < 4; k++) {
    Pack8 o;
    #pragma unroll
    for (int u = 0; u < 8; u++) o.h[u] = sg[ch0 + u][k * 64 + sp];
    const int gp = (y0 + k) * 128 + xh * 64 + sp;
    *(i32x4*)&gt[((size_t)z * HW_ + gp) * 512 + cz * 32 + ch0] = o.v;
  }
}

// ---------------------------------------------------------------------------
extern "C" void kernel_launch(void* const* d_in, const int* in_sizes, int n_in,
                              void* d_out, int out_size, void* d_ws, size_t ws_size,
                              hipStream_t stream) {
  const float* x     = (const float*)d_in[0];
  const float* temp  = (const float*)d_in[1];
  const float* ln1w  = (const float*)d_in[2];
  const float* ln1b  = (const float*)d_in[3];
  const float* ln2w  = (const float*)d_in[4];
  const float* ln2b  = (const float*)d_in[5];
  const float* wqkv  = (const float*)d_in[6];
  const float* wqkvdw= (const float*)d_in[7];
  const float* wproj = (const float*)d_in[8];
  const float* win   = (const float*)d_in[9];
  const float* wdw   = (const float*)d_in[10];
  const float* wout  = (const float*)d_in[11];
  float* out = (float*)d_out;
  char* ws = (char*)d_ws;

  const int HW = 16384;
  const size_t HWC = (size_t)192 * HW;

  __hip_bfloat16* yt    = (__hip_bfloat16*)(ws + 0);
  __hip_bfloat16* qkva  = (__hip_bfloat16*)(ws + 25165824);
  __hip_bfloat16* qkvb  = (__hip_bfloat16*)(ws + 100663296);
  __hip_bfloat16* hbuf  = (__hip_bfloat16*)(ws + 25165824);   // aliases dead qkva/qkvb
  float*          xa    = (float*)(ws + 176160768);
  __hip_bfloat16* gt    = (__hip_bfloat16*)(ws + 226492416);  // 2 half-batches
  __hip_bfloat16* wqkvB = (__hip_bfloat16*)(ws + 260046848);
  __hip_bfloat16* wprojB= (__hip_bfloat16*)(ws + 260268032);
  __hip_bfloat16* winB  = (__hip_bfloat16*)(ws + 260341760);
  __hip_bfloat16* woutB = (__hip_bfloat16*)(ws + 260734976);
  float*          nrm2p = (float*)(ws + 260931584);
  float*          Gpart = (float*)(ws + 260980736);
  float*          P     = (float*)(ws + 263340032);

  convert_weights<<<768, 256, 0, stream>>>(wqkv, wproj, win, wout,
                                           wqkvB, wprojB, winB, woutB);

  // 1. yt = LN1(x), all batches
  ln_t_kernel<<<dim3(256, 4), 256, 0, stream>>>(x, ln1w, ln1b, yt);
  // 2. qkva = w_qkv @ y   (576 x 16384) x4 — B-stationary, 64-col panels
  gemm_bstat<0><<<dim3(256, 4), 256, 0, stream>>>(
      wqkvB, yt, nullptr, qkva, 9, (size_t)HW * 192, 0, (size_t)576 * HW);
  // 3. qkvb = dwconv3x3(qkva) + nrm2 partials
  dw_kernel<<<dim3(8, 576, 4), 256, 0, stream>>>(qkva, wqkvdw, qkvb, nrm2p);
  // 4. Gram partials via MFMA
  gram_kernel<<<dim3(8, 32, 4), 256, 0, stream>>>(qkvb, Gpart);
  // 5. P = softmax(reduce(Gpart) * temp / (|q||k|))
  softmax2_kernel<<<dim3(8, 4), 256, 0, stream>>>(Gpart, nrm2p, temp, P);
  // 6. yt = (P @ v)^T bf16
  pv_kernel<<<dim3(8, 64, 4), 256, 0, stream>>>(P, qkvb, yt);
  // 7. xa = x + w_proj @ pv — B-stationary with residual epilogue
  gemm_bstat<1><<<dim3(256, 4), 256, 0, stream>>>(
      wprojB, yt, x, xa, 3, (size_t)HW * 192, HWC, HWC);
  // 8. yt = LN2(xa)
  ln_t_kernel<<<dim3(256, 4), 256, 0, stream>>>(xa, ln2w, ln2b, yt);
  // 9. hbuf = w_in @ y   (1024 x 16384) x4 — B-stationary (rows>=1020 zero)
  gemm_bstat<0><<<dim3(256, 4), 256, 0, stream>>>(
      winB, yt, nullptr, hbuf, 16, (size_t)HW * 192, 0, (size_t)1024 * HW);
  // 10-13. FFN tail in two half-batches: gate(+transpose) then w_out GEMM
  for (int half = 0; half < 2; half++) {
    const int b0 = half * 2;
    dwg_t_kernel<<<dim3(64, 16, 2), 256, 0, stream>>>(hbuf, wdw, gt, b0);
    mfma_gemm<1><<<dim3(3, 128, 2), 256, 0, stream>>>(
        woutB, gt, xa + (size_t)b0 * HWC, out + (size_t)b0 * HWC,
        192, HW, 512, (size_t)HW * 512, HWC, HWC);
  }
}

// Round 9
// 460.360 us; speedup vs baseline: 1.1055x; 1.0236x over previous
//
#include <hip/hip_runtime.h>
#include <hip/hip_bf16.h>
#include <math.h>

// ---------------------------------------------------------------------------
// Round 16 = r15's dw/dwg kernels + gemm_bstat back to the measured-best
// 128-col r12 structure, with ONE reorder: stores issue AFTER the second
// barrier (MFMA -> bar -> ds_write As -> bar -> store). r12 issued stores
// right before barrier-1, whose implicit vmcnt(0) drained them on the
// critical path (2 blocks/CU -> nothing hides it). Now the drain point is a
// full MFMA phase later. 64-col r15 variant measured worse (53.7 vs 46.3):
// tile-halving doubles barrier+staging cost per byte — reverted.
//
// ws layout (bytes):
//   yt4    @ 0            25,165,824  bf16 [b][p][192]
//   qkva4  @ 25,165,824   75,497,472  bf16 [b][576][p]
//   qkvb4  @ 100,663,296  75,497,472  bf16 [b][576][p]
//   hbuf4  @ 25,165,824  134,217,728  bf16 [b][1024][p]  (aliases dead qkva/qkvb)
//   xa4    @ 176,160,768  50,331,648  fp32 [b][192][p]
//   gt2    @ 226,492,416  33,554,432  bf16 [z][p][512]   (half-batch)
//   wqkvB  @ 260,046,848     221,184
//   wprojB @ 260,268,032      73,728
//   winB   @ 260,341,760     393,216  (1024x192, rows >=1020 zero)
//   woutB  @ 260,734,976     196,608  (192x512, cols >=510 zero)
//   nrm2p  @ 260,931,584      49,152  fp32 [b][384][8]
//   Gpart  @ 260,980,736   2,359,296  fp32 [b][32][8][576]
//   P      @ 263,340,032      73,728  fp32 [b][8][576]
// total 263,413,760 <= 268,435,456. No atomics, no memsets.
// ---------------------------------------------------------------------------

#define HW_ 16384

typedef __attribute__((ext_vector_type(8))) short bf16x8;
typedef __attribute__((ext_vector_type(4))) float f32x4;
typedef __attribute__((ext_vector_type(16))) float f32x16;
typedef __attribute__((ext_vector_type(4))) int i32x4;

union Pack8 { __hip_bfloat16 h[8]; i32x4 v; };

// ---- weight fp32 -> bf16 conversion (with padding) -------------------------
__global__ __launch_bounds__(256) void convert_weights(
    const float* __restrict__ wqkv, const float* __restrict__ wproj,
    const float* __restrict__ win, const float* __restrict__ wout,
    __hip_bfloat16* __restrict__ oq, __hip_bfloat16* __restrict__ op,
    __hip_bfloat16* __restrict__ oi, __hip_bfloat16* __restrict__ oo) {
  const int i = blockIdx.x * 256 + threadIdx.x;
  if (i < 110592) oq[i] = __float2bfloat16(wqkv[i]);            // 576x192
  if (i < 36864)  op[i] = __float2bfloat16(wproj[i]);           // 192x192
  if (i < 196608) {                                             // 1024x192 pad
    int m = i / 192, k = i - m * 192;
    oi[i] = __float2bfloat16(m < 1020 ? win[m * 192 + k] : 0.f);
  }
  if (i < 98304) {                                              // 192x512 pad
    int m = i >> 9, k = i & 511;
    oo[i] = __float2bfloat16(k < 510 ? wout[m * 510 + k] : 0.f);
  }
}

// ---- channel LN -> transposed bf16 output [p][192]; grid (256, batch) ------
__global__ __launch_bounds__(256) void ln_t_kernel(
    const float* __restrict__ x, const float* __restrict__ w,
    const float* __restrict__ bi, __hip_bfloat16* __restrict__ yt) {
  const int b = blockIdx.y;
  x += (size_t)b * 192 * HW_;
  yt += (size_t)b * HW_ * 192;
  __shared__ float tile[192][68];
  __shared__ float psum[4][64], psq[4][64];
  __shared__ float mu_s[64], inv_s[64];
  const int tid = threadIdx.x;
  const int p0 = blockIdx.x * 64;
  for (int idx = tid; idx < 192 * 16; idx += 256) {
    int c = idx >> 4, p4 = idx & 15;
    f32x4 v = *(const f32x4*)(x + (size_t)c * HW_ + p0 + p4 * 4);
    *(f32x4*)&tile[c][p4 * 4] = v;
  }
  __syncthreads();
  const int tx = tid & 63, ty = tid >> 6;
  float s = 0.f, s2 = 0.f;
  for (int c = ty * 48; c < ty * 48 + 48; c++) {
    float v = tile[c][tx]; s += v; s2 += v * v;
  }
  psum[ty][tx] = s; psq[ty][tx] = s2;
  __syncthreads();
  if (ty == 0) {
    float ts = psum[0][tx] + psum[1][tx] + psum[2][tx] + psum[3][tx];
    float ts2 = psq[0][tx] + psq[1][tx] + psq[2][tx] + psq[3][tx];
    float mu = ts * (1.f / 192.f);
    float var = ts2 * (1.f / 192.f) - mu * mu;
    mu_s[tx] = mu; inv_s[tx] = rsqrtf(var + 1e-5f);
  }
  __syncthreads();
  for (int idx = tid; idx < 64 * 24; idx += 256) {
    int c8 = idx % 24, p = idx / 24;
    float mu = mu_s[p], inv = inv_s[p];
    Pack8 pk;
    #pragma unroll
    for (int u = 0; u < 8; u++) {
      int c = c8 * 8 + u;
      pk.h[u] = __float2bfloat16((tile[c][p] - mu) * inv * w[c] + bi[c]);
    }
    *(i32x4*)&yt[(size_t)(p0 + p) * 192 + c8 * 8] = pk.v;
  }
}

// ---- B-stationary MFMA GEMM, 128-col panels (r12 structure, stores moved
// after barrier-2): D[M][HW] = A[M][192] @ B[HW][192]^T. grid (HW/128, b).
// XOR-swizzled LDS, conflict-free b128. EPI=0: bf16 out. EPI=1: fp32 + res C.
template <int EPI>
__global__ __launch_bounds__(256) void gemm_bstat(
    const __hip_bfloat16* __restrict__ A, const __hip_bfloat16* __restrict__ Bg,
    const float* __restrict__ Cres, void* __restrict__ Dout,
    int Mtiles, size_t Bstr, size_t Cstr, size_t Dstr) {
  const int z = blockIdx.y;
  const __hip_bfloat16* B = Bg + (size_t)z * Bstr;
  const int col0 = blockIdx.x * 128;
  __shared__ __align__(16) __hip_bfloat16 Bs[128][192];
  __shared__ __align__(16) __hip_bfloat16 As[64][192];
  const int tid = threadIdx.x;
  const int wave = tid >> 6, lane = tid & 63;
  const int quad = lane >> 4, lr = lane & 15;
  const int wm = (wave & 1) * 32, wn = (wave >> 1) * 64;
  const int lrx = lr & 7;                      // read-side XOR (row&7 == lrx)

  const int arow = tid >> 3, ach = tid & 7;    // staging coords (32 rows x 8 ch)
  const int achs = ach ^ (arow & 7);           // swizzled chunk base

  // --- load B panel (once), swizzled ---
  #pragma unroll
  for (int l = 0; l < 4; l++) {
    const int row = arow + 32 * l;
    const __hip_bfloat16* bp = B + (size_t)(col0 + row) * 192;
    #pragma unroll
    for (int j = 0; j < 3; j++) {
      i32x4 v = *(const i32x4*)(bp + (ach + 8 * j) * 8);
      *(i32x4*)&Bs[row][(achs + 8 * j) * 8] = v;
    }
  }
  // --- prefetch A tile 0 to regs ---
  i32x4 areg[6];
  #pragma unroll
  for (int l = 0; l < 2; l++)
    #pragma unroll
    for (int j = 0; j < 3; j++)
      areg[l * 3 + j] = *(const i32x4*)(
          A + (size_t)(arow + 32 * l) * 192 + (ach + 8 * j) * 8);
  // --- stage A tile 0 ---
  #pragma unroll
  for (int l = 0; l < 2; l++)
    #pragma unroll
    for (int j = 0; j < 3; j++)
      *(i32x4*)&As[arow + 32 * l][(achs + 8 * j) * 8] = areg[l * 3 + j];
  __syncthreads();

  for (int mt = 0; mt < Mtiles; mt++) {
    const int row0 = mt * 64;
    if (mt + 1 < Mtiles) {                     // issue next A loads (L2-hit)
      const __hip_bfloat16* ap = A + (size_t)(mt + 1) * 64 * 192;
      #pragma unroll
      for (int l = 0; l < 2; l++)
        #pragma unroll
        for (int j = 0; j < 3; j++)
          areg[l * 3 + j] = *(const i32x4*)(
              ap + (size_t)(arow + 32 * l) * 192 + (ach + 8 * j) * 8);
    }
    f32x4 acc[2][4];
    #pragma unroll
    for (int i = 0; i < 2; i++)
      #pragma unroll
      for (int j = 0; j < 4; j++) acc[i][j] = (f32x4){0.f, 0.f, 0.f, 0.f};
    #pragma unroll
    for (int kc = 0; kc < 6; kc++) {
      const int chq = ((kc * 4 + quad) ^ lrx) * 8;
      bf16x8 a0 = *(const bf16x8*)&As[wm + lr][chq];
      bf16x8 a1 = *(const bf16x8*)&As[wm + 16 + lr][chq];
      #pragma unroll
      for (int j = 0; j < 4; j++) {
        bf16x8 bb = *(const bf16x8*)&Bs[wn + j * 16 + lr][chq];
        acc[0][j] = __builtin_amdgcn_mfma_f32_16x16x32_bf16(a0, bb, acc[0][j], 0, 0, 0);
        acc[1][j] = __builtin_amdgcn_mfma_f32_16x16x32_bf16(a1, bb, acc[1][j], 0, 0, 0);
      }
    }
    __syncthreads();                           // waves done reading As;
                                               // drains stores(mt-1), issued
                                               // one full MFMA phase ago
    if (mt + 1 < Mtiles) {
      #pragma unroll
      for (int l = 0; l < 2; l++)
        #pragma unroll
        for (int j = 0; j < 3; j++)
          *(i32x4*)&As[arow + 32 * l][(achs + 8 * j) * 8] = areg[l * 3 + j];
      __syncthreads();
    }
    // stores issued AFTER the barriers: they overlap tile mt+1's MFMAs and
    // are drained only at the next iteration's first barrier.
    #pragma unroll
    for (int i = 0; i < 2; i++)
      #pragma unroll
      for (int r = 0; r < 4; r++) {
        const int gm = row0 + wm + i * 16 + quad * 4 + r;
        const size_t base = (size_t)gm * HW_ + col0 + wn + lr;
        if (EPI == 0) {
          __hip_bfloat16* dp = (__hip_bfloat16*)Dout + (size_t)z * Dstr + base;
          #pragma unroll
          for (int j = 0; j < 4; j++) dp[j * 16] = __float2bfloat16(acc[i][j][r]);
        } else {
          float* dp = (float*)Dout + (size_t)z * Dstr + base;
          const float* cp = Cres + (size_t)z * Cstr + base;
          #pragma unroll
          for (int j = 0; j < 4; j++) dp[j * 16] = acc[i][j][r] + cp[j * 16];
        }
      }
  }
}

// ---- MFMA GEMM: D[M][N] = A[M][K] @ B_t[N][K]^T (+res); z = batch ----------
// (kept for w_out; XOR-swizzled LDS, no pad)
template <int EPI>
__global__ __launch_bounds__(256) void mfma_gemm(
    const __hip_bfloat16* __restrict__ A, const __hip_bfloat16* __restrict__ Bg,
    const float* __restrict__ Cres, void* __restrict__ Dout,
    int M, int N, int K, size_t Bstr, size_t Cstr, size_t Dstr) {
  const int z = blockIdx.z;
  const __hip_bfloat16* B = Bg + (size_t)z * Bstr;
  const float* C = Cres ? Cres + (size_t)z * Cstr : nullptr;
  __shared__ __align__(16) __hip_bfloat16 As[64][64];
  __shared__ __align__(16) __hip_bfloat16 Bs[128][64];
  const int tid = threadIdx.x;
  const int wave = tid >> 6, lane = tid & 63;
  const int quad = lane >> 4, lr = lane & 15;
  const int lrx = lr & 7;
  const int wm = (wave & 1) * 32, wn = (wave >> 1) * 64;
  const int row0 = blockIdx.x * 64, col0 = blockIdx.y * 128;

  f32x4 acc[2][4];
  #pragma unroll
  for (int i = 0; i < 2; i++)
    #pragma unroll
    for (int j = 0; j < 4; j++) acc[i][j] = (f32x4){0.f, 0.f, 0.f, 0.f};

  for (int k0 = 0; k0 < K; k0 += 64) {
    #pragma unroll
    for (int l = 0; l < 2; l++) {
      int t = tid + l * 256;
      int row = t >> 3, ch = t & 7;
      i32x4 v = *(const i32x4*)(A + (size_t)(row0 + row) * K + k0 + ch * 8);
      *(i32x4*)&As[row][(ch ^ (row & 7)) * 8] = v;
    }
    #pragma unroll
    for (int l = 0; l < 4; l++) {
      int t = tid + l * 256;
      int row = t >> 3, ch = t & 7;
      i32x4 v = *(const i32x4*)(B + (size_t)(col0 + row) * K + k0 + ch * 8);
      *(i32x4*)&Bs[row][(ch ^ (row & 7)) * 8] = v;
    }
    __syncthreads();
    #pragma unroll
    for (int ks = 0; ks < 2; ks++) {
      const int chq = ((ks * 4 + quad) ^ lrx) * 8;
      bf16x8 a0 = *(const bf16x8*)&As[wm + lr][chq];
      bf16x8 a1 = *(const bf16x8*)&As[wm + 16 + lr][chq];
      #pragma unroll
      for (int j = 0; j < 4; j++) {
        bf16x8 bb = *(const bf16x8*)&Bs[wn + j * 16 + lr][chq];
        acc[0][j] = __builtin_amdgcn_mfma_f32_16x16x32_bf16(a0, bb, acc[0][j], 0, 0, 0);
        acc[1][j] = __builtin_amdgcn_mfma_f32_16x16x32_bf16(a1, bb, acc[1][j], 0, 0, 0);
      }
    }
    __syncthreads();
  }

  #pragma unroll
  for (int i = 0; i < 2; i++) {
    #pragma unroll
    for (int r = 0; r < 4; r++) {
      int gm = row0 + wm + i * 16 + quad * 4 + r;
      if (gm >= M) continue;
      #pragma unroll
      for (int j = 0; j < 4; j++) {
        int gn = col0 + wn + j * 16 + lr;
        size_t idx = (size_t)gm * N + gn;
        if (EPI == 0) {
          (((__hip_bfloat16*)Dout) + (size_t)z * Dstr)[idx] = __float2bfloat16(acc[i][j][r]);
        } else {
          (((float*)Dout) + (size_t)z * Dstr)[idx] = acc[i][j][r] + C[idx];
        }
      }
    }
  }
}

// ---- depthwise 3x3 (8 px/thread) + fused q,k sum-of-squares partials -------
// branchless clamped row loads (hoistable) + shfl halos
__global__ __launch_bounds__(256) void dw_kernel(
    const __hip_bfloat16* __restrict__ in, const float* __restrict__ wdw,
    __hip_bfloat16* __restrict__ out, float* __restrict__ nrm2p) {
  const int b = blockIdx.z;
  in  += (size_t)b * 576 * HW_;
  out += (size_t)b * 576 * HW_;
  const int c = blockIdx.y;
  const int x8 = threadIdx.x & 15;
  const int y = blockIdx.x * 16 + (threadIdx.x >> 4);
  const __hip_bfloat16* ip = in + (size_t)c * HW_;
  const float* wp = wdw + c * 9;
  float wv[9];
  #pragma unroll
  for (int u = 0; u < 9; u++) wv[u] = wp[u];
  i32x4 vrow[3]; float vf[3];
  #pragma unroll
  for (int r = 0; r < 3; r++) {
    const int yy = y + r - 1;
    const int yyc = yy < 0 ? 0 : (yy > 127 ? 127 : yy);
    vf[r] = (yy >= 0 && yy < 128) ? 1.f : 0.f;
    vrow[r] = *(const i32x4*)(ip + yyc * 128 + x8 * 8);
  }
  float acc[8];
  #pragma unroll
  for (int j = 0; j < 8; j++) acc[j] = 0.f;
  #pragma unroll
  for (int r = 0; r < 3; r++) {
    Pack8 mid; mid.v = vrow[r];
    const int hi = vrow[r][3];
    const int lo = vrow[r][0];
    const int lw = __shfl_up(hi, 1, 64);
    const int rw = __shfl_down(lo, 1, 64);
    float row[10];
    row[0] = (x8 > 0) ? vf[r] * (float)(((const __hip_bfloat16*)&lw)[1]) : 0.f;
    #pragma unroll
    for (int u = 0; u < 8; u++) row[1 + u] = vf[r] * (float)mid.h[u];
    row[9] = (x8 < 15) ? vf[r] * (float)(((const __hip_bfloat16*)&rw)[0]) : 0.f;
    const float wl = wv[r * 3], wc = wv[r * 3 + 1], wr = wv[r * 3 + 2];
    #pragma unroll
    for (int j = 0; j < 8; j++)
      acc[j] += wl * row[j] + wc * row[j + 1] + wr * row[j + 2];
  }
  Pack8 o;
  #pragma unroll
  for (int j = 0; j < 8; j++) o.h[j] = __float2bfloat16(acc[j]);
  *(i32x4*)(out + (size_t)c * HW_ + y * 128 + x8 * 8) = o.v;
  if (c < 384) {
    float s = 0.f;
    #pragma unroll
    for (int j = 0; j < 8; j++) s += acc[j] * acc[j];
    #pragma unroll
    for (int off = 32; off > 0; off >>= 1) s += __shfl_down(s, off, 64);
    __shared__ float wsum[4];
    const int lane = threadIdx.x & 63, wvi = threadIdx.x >> 6;
    if (lane == 0) wsum[wvi] = s;
    __syncthreads();
    if (threadIdx.x == 0)
      nrm2p[((size_t)b * 384 + c) * 8 + blockIdx.x] =
          wsum[0] + wsum[1] + wsum[2] + wsum[3];
  }
}

// ---- MFMA Gram partials; grid (8 heads, 32 chunks, 4 batch) ----------------
__global__ __launch_bounds__(256) void gram_kernel(
    const __hip_bfloat16* __restrict__ qkv, float* __restrict__ Gpart) {
  const int b = blockIdx.z;
  qkv   += (size_t)b * 576 * HW_;
  Gpart += (size_t)b * 32 * 8 * 576;
  const int h = blockIdx.x, chunk = blockIdx.y;
  const int tid = threadIdx.x;
  const int w = tid >> 6, lane = tid & 63;
  const int m = lane & 31;
  const int khalf = lane >> 5;
  const __hip_bfloat16* qb = qkv + (size_t)(h * 24) * HW_;
  const __hip_bfloat16* kb = qkv + (size_t)(192 + h * 24) * HW_;
  f32x16 acc;
  #pragma unroll
  for (int i = 0; i < 16; i++) acc[i] = 0.f;
  const int e0 = chunk * 512 + w * 128;
  #pragma unroll
  for (int j = 0; j < 8; j++) {
    const int k0 = e0 + j * 16 + khalf * 8;
    bf16x8 a = *(const bf16x8*)(qb + (size_t)m * HW_ + k0);
    bf16x8 bfr = *(const bf16x8*)(kb + (size_t)m * HW_ + k0);
    acc = __builtin_amdgcn_mfma_f32_32x32x16_bf16(a, bfr, acc, 0, 0, 0);
  }
  __shared__ float gs[4][576];
  #pragma unroll
  for (int r = 0; r < 16; r++) {
    int row = (r & 3) + 8 * (r >> 2) + 4 * khalf;
    if (row < 24 && m < 24) gs[w][row * 24 + m] = acc[r];
  }
  __syncthreads();
  float* gp = Gpart + (size_t)(chunk * 8 + h) * 576;
  for (int t = tid; t < 576; t += 256)
    gp[t] = gs[0][t] + gs[1][t] + gs[2][t] + gs[3][t];
}

// ---- reduce Gpart + nrm2p partials, softmax -> P; grid (8 heads, 4 batch) --
__global__ __launch_bounds__(256) void softmax2_kernel(
    const float* __restrict__ Gpart, const float* __restrict__ nrm2p,
    const float* __restrict__ temp, float* __restrict__ P) {
  const int b = blockIdx.y;
  Gpart += (size_t)b * 32 * 8 * 576;
  nrm2p += (size_t)b * 384 * 8;
  P     += (size_t)b * 8 * 576;
  const int h = blockIdx.x;
  const int tid = threadIdx.x;
  __shared__ float Gs[576];
  __shared__ float nq[24], nk[24];
  for (int t = tid; t < 576; t += 256) {
    float s = 0.f;
    for (int ch = 0; ch < 32; ch++)
      s += Gpart[(size_t)(ch * 8 + h) * 576 + t];
    Gs[t] = s;
  }
  if (tid < 48) {
    const int r = (tid < 24) ? (h * 24 + tid) : (192 + h * 24 + tid - 24);
    float s = 0.f;
    #pragma unroll
    for (int j = 0; j < 8; j++) s += nrm2p[(size_t)r * 8 + j];
    float nv = fmaxf(sqrtf(s), 1e-12f);
    if (tid < 24) nq[tid] = nv; else nk[tid - 24] = nv;
  }
  __syncthreads();
  if (tid < 24) {
    const int d = tid;
    const float tp = temp[h];
    float row[24], mx = -1e30f;
    #pragma unroll
    for (int c = 0; c < 24; c++) {
      float v = Gs[d * 24 + c] * tp / (nq[d] * nk[c]);
      row[c] = v; mx = fmaxf(mx, v);
    }
    float s = 0.f;
    #pragma unroll
    for (int c = 0; c < 24; c++) { float e = expf(row[c] - mx); row[c] = e; s += e; }
    const float inv = 1.f / s;
    #pragma unroll
    for (int c = 0; c < 24; c++) P[h * 576 + d * 24 + c] = row[c] * inv;
  }
}

// ---- out_t[e][h*24+d] = sum_c P[h,d,c]*v[h,c,e]; grid (8, 64, 4) -----------
__global__ __launch_bounds__(256) void pv_kernel(
    const float* __restrict__ P, const __hip_bfloat16* __restrict__ qkv,
    __hip_bfloat16* __restrict__ yt) {
  const int b = blockIdx.z;
  P   += (size_t)b * 8 * 576;
  qkv += (size_t)b * 576 * HW_;
  yt  += (size_t)b * HW_ * 192;
  const int hh = blockIdx.x;
  const int e = blockIdx.y * 256 + threadIdx.x;
  __shared__ float Ps[576];
  for (int t = threadIdx.x; t < 576; t += 256) Ps[t] = P[hh * 576 + t];
  __syncthreads();
  const __hip_bfloat16* vb = qkv + (size_t)(384 + hh * 24) * HW_;
  float acc[24];
  #pragma unroll
  for (int d = 0; d < 24; d++) acc[d] = 0.f;
  for (int c = 0; c < 24; c++) {
    float v = (float)vb[(size_t)c * HW_ + e];
    #pragma unroll
    for (int d = 0; d < 24; d++) acc[d] += Ps[d * 24 + c] * v;
  }
  #pragma unroll
  for (int g = 0; g < 3; g++) {
    Pack8 pk;
    #pragma unroll
    for (int u = 0; u < 8; u++) pk.h[u] = __float2bfloat16(acc[g * 8 + u]);
    *(i32x4*)&yt[(size_t)e * 192 + hh * 24 + g * 8] = pk.v;
  }
}

// ---- FFN depthwise + GELU gate -> transposed gt[p][512], 4-row tiles -------
// v3: branchless clamped row loads (all 12 dwordx4 issue upfront), shfl
// halos, edge lanes via 2 small branches. grid (64, 16, 2).
__global__ __launch_bounds__(256) void dwg_t_kernel(
    const __hip_bfloat16* __restrict__ hsrc, const float* __restrict__ wdw,
    __hip_bfloat16* __restrict__ gt, int b0) {
  const int z = blockIdx.z;
  const int bb = b0 + z;
  const int yt = blockIdx.x >> 1, xh = blockIdx.x & 1;
  const int cz = blockIdx.y;
  const int tid = threadIdx.x;
  const int cl = tid >> 3, x8 = tid & 7;         // 32 ch x 8 px-groups
  const int c = cz * 32 + cl;
  const int y0 = yt * 4;
  const int pxb = xh * 64 + x8 * 8;              // global px base
  __shared__ __hip_bfloat16 sg[32][266];         // [ch][4*64] pad->266

  const bool active = (c < 510);
  const int ca = active ? c : 0;
  const __hip_bfloat16* ha = hsrc + ((size_t)bb * 1024 + ca) * HW_;
  const __hip_bfloat16* hb = hsrc + ((size_t)bb * 1024 + ca + 510) * HW_;
  float wva[9], wvb[9];
  #pragma unroll
  for (int u = 0; u < 9; u++) {
    wva[u] = active ? wdw[c * 9 + u] : 0.f;
    wvb[u] = active ? wdw[(c + 510) * 9 + u] : 0.f;
  }

  // phase 1: all 6 row-pair loads with clamped row index (unconditional)
  i32x4 va[6], vbv[6];
  float vf[6];
  int offr[6];
  #pragma unroll
  for (int i = 0; i < 6; i++) {
    const int ry = y0 - 1 + i;
    const int ryc = ry < 0 ? 0 : (ry > 127 ? 127 : ry);
    vf[i] = (ry >= 0 && ry < 128) ? 1.f : 0.f;
    offr[i] = ryc * 128 + pxb;
    va[i]  = *(const i32x4*)(ha + offr[i]);
    vbv[i] = *(const i32x4*)(hb + offr[i]);
  }
  // phase 2: edge halos (only the block-boundary lanes need real loads)
  float leA[6], leB[6], reA[6], reB[6];
  #pragma unroll
  for (int i = 0; i < 6; i++) { leA[i] = 0.f; leB[i] = 0.f; reA[i] = 0.f; reB[i] = 0.f; }
  if (x8 == 0 && xh == 1) {
    #pragma unroll
    for (int i = 0; i < 6; i++) {
      leA[i] = vf[i] * (float)ha[offr[i] - 1];
      leB[i] = vf[i] * (float)hb[offr[i] - 1];
    }
  }
  if (x8 == 7 && xh == 0) {
    #pragma unroll
    for (int i = 0; i < 6; i++) {
      reA[i] = vf[i] * (float)ha[offr[i] + 8];
      reB[i] = vf[i] * (float)hb[offr[i] + 8];
    }
  }

  float aA[3][8], aB[3][8];
  #pragma unroll
  for (int s = 0; s < 3; s++)
    #pragma unroll
    for (int j = 0; j < 8; j++) { aA[s][j] = 0.f; aB[s][j] = 0.f; }

  #pragma unroll
  for (int i = 0; i < 6; i++) {
    const int hiA = va[i][3],  loA = va[i][0];
    const int hiB = vbv[i][3], loB = vbv[i][0];
    const int lwA = __shfl_up(hiA, 1, 64), rwA = __shfl_down(loA, 1, 64);
    const int lwB = __shfl_up(hiB, 1, 64), rwB = __shfl_down(loB, 1, 64);
    Pack8 ma; ma.v = va[i];
    Pack8 mb; mb.v = vbv[i];
    float ra[10], rb[10];
    ra[0] = (x8 > 0) ? vf[i] * (float)(((const __hip_bfloat16*)&lwA)[1]) : leA[i];
    rb[0] = (x8 > 0) ? vf[i] * (float)(((const __hip_bfloat16*)&lwB)[1]) : leB[i];
    #pragma unroll
    for (int u = 0; u < 8; u++) {
      ra[1 + u] = vf[i] * (float)ma.h[u];
      rb[1 + u] = vf[i] * (float)mb.h[u];
    }
    ra[9] = (x8 < 7) ? vf[i] * (float)(((const __hip_bfloat16*)&rwA)[0]) : reA[i];
    rb[9] = (x8 < 7) ? vf[i] * (float)(((const __hip_bfloat16*)&rwB)[0]) : reB[i];
    // input row feeds output rows lo = i-r (weight-row r)
    #pragma unroll
    for (int r = 0; r < 3; r++) {
      const int lo = i - r;
      if (lo < 0 || lo >= 4) continue;
      const int s = lo % 3;
      const float a0 = wva[r * 3], a1 = wva[r * 3 + 1], a2 = wva[r * 3 + 2];
      const float b0w = wvb[r * 3], b1 = wvb[r * 3 + 1], b2 = wvb[r * 3 + 2];
      #pragma unroll
      for (int j = 0; j < 8; j++) {
        aA[s][j] += a0 * ra[j] + a1 * ra[j + 1] + a2 * ra[j + 2];
        aB[s][j] += b0w * rb[j] + b1 * rb[j + 1] + b2 * rb[j + 2];
      }
    }
    // output row lo = i-2 complete: gate + stage to LDS, recycle slot
    {
      const int lo = i - 2;
      if (lo >= 0 && lo < 4) {
        const int s = lo % 3;
        Pack8 o;
        #pragma unroll
        for (int j = 0; j < 8; j++) {
          float v = aA[s][j];
          float ge = 0.5f * v * (1.f + erff(v * 0.70710678118654752f));
          o.h[j] = __float2bfloat16(ge * aB[s][j]);
          aA[s][j] = 0.f; aB[s][j] = 0.f;
        }
        *(i32x4*)&sg[cl][lo * 64 + x8 * 8] = o.v;
      }
    }
  }
  __syncthreads();
  // transposed write: 256 local px x 32 ch; 4 lanes cover one 64B px segment
  const int sp = tid >> 2, ch0 = (tid & 3) * 8;
  #pragma unroll
  for (int k = 0; k < 4; k++) {
    Pack8 o;
    #pragma unroll
    for (int u = 0; u < 8; u++) o.h[u] = sg[ch0 + u][k * 64 + sp];
    const int gp = (y0 + k) * 128 + xh * 64 + sp;
    *(i32x4*)&gt[((size_t)z * HW_ + gp) * 512 + cz * 32 + ch0] = o.v;
  }
}

// ---------------------------------------------------------------------------
extern "C" void kernel_launch(void* const* d_in, const int* in_sizes, int n_in,
                              void* d_out, int out_size, void* d_ws, size_t ws_size,
                              hipStream_t stream) {
  const float* x     = (const float*)d_in[0];
  const float* temp  = (const float*)d_in[1];
  const float* ln1w  = (const float*)d_in[2];
  const float* ln1b  = (const float*)d_in[3];
  const float* ln2w  = (const float*)d_in[4];
  const float* ln2b  = (const float*)d_in[5];
  const float* wqkv  = (const float*)d_in[6];
  const float* wqkvdw= (const float*)d_in[7];
  const float* wproj = (const float*)d_in[8];
  const float* win   = (const float*)d_in[9];
  const float* wdw   = (const float*)d_in[10];
  const float* wout  = (const float*)d_in[11];
  float* out = (float*)d_out;
  char* ws = (char*)d_ws;

  const int HW = 16384;
  const size_t HWC = (size_t)192 * HW;

  __hip_bfloat16* yt    = (__hip_bfloat16*)(ws + 0);
  __hip_bfloat16* qkva  = (__hip_bfloat16*)(ws + 25165824);
  __hip_bfloat16* qkvb  = (__hip_bfloat16*)(ws + 100663296);
  __hip_bfloat16* hbuf  = (__hip_bfloat16*)(ws + 25165824);   // aliases dead qkva/qkvb
  float*          xa    = (float*)(ws + 176160768);
  __hip_bfloat16* gt    = (__hip_bfloat16*)(ws + 226492416);  // 2 half-batches
  __hip_bfloat16* wqkvB = (__hip_bfloat16*)(ws + 260046848);
  __hip_bfloat16* wprojB= (__hip_bfloat16*)(ws + 260268032);
  __hip_bfloat16* winB  = (__hip_bfloat16*)(ws + 260341760);
  __hip_bfloat16* woutB = (__hip_bfloat16*)(ws + 260734976);
  float*          nrm2p = (float*)(ws + 260931584);
  float*          Gpart = (float*)(ws + 260980736);
  float*          P     = (float*)(ws + 263340032);

  convert_weights<<<768, 256, 0, stream>>>(wqkv, wproj, win, wout,
                                           wqkvB, wprojB, winB, woutB);

  // 1. yt = LN1(x), all batches
  ln_t_kernel<<<dim3(256, 4), 256, 0, stream>>>(x, ln1w, ln1b, yt);
  // 2. qkva = w_qkv @ y   (576 x 16384) x4 — B-stationary, 128-col panels
  gemm_bstat<0><<<dim3(128, 4), 256, 0, stream>>>(
      wqkvB, yt, nullptr, qkva, 9, (size_t)HW * 192, 0, (size_t)576 * HW);
  // 3. qkvb = dwconv3x3(qkva) + nrm2 partials
  dw_kernel<<<dim3(8, 576, 4), 256, 0, stream>>>(qkva, wqkvdw, qkvb, nrm2p);
  // 4. Gram partials via MFMA
  gram_kernel<<<dim3(8, 32, 4), 256, 0, stream>>>(qkvb, Gpart);
  // 5. P = softmax(reduce(Gpart) * temp / (|q||k|))
  softmax2_kernel<<<dim3(8, 4), 256, 0, stream>>>(Gpart, nrm2p, temp, P);
  // 6. yt = (P @ v)^T bf16
  pv_kernel<<<dim3(8, 64, 4), 256, 0, stream>>>(P, qkvb, yt);
  // 7. xa = x + w_proj @ pv — B-stationary with residual epilogue
  gemm_bstat<1><<<dim3(128, 4), 256, 0, stream>>>(
      wprojB, yt, x, xa, 3, (size_t)HW * 192, HWC, HWC);
  // 8. yt = LN2(xa)
  ln_t_kernel<<<dim3(256, 4), 256, 0, stream>>>(xa, ln2w, ln2b, yt);
  // 9. hbuf = w_in @ y   (1024 x 16384) x4 — B-stationary (rows>=1020 zero)
  gemm_bstat<0><<<dim3(128, 4), 256, 0, stream>>>(
      winB, yt, nullptr, hbuf, 16, (size_t)HW * 192, 0, (size_t)1024 * HW);
  // 10-13. FFN tail in two half-batches: gate(+transpose) then w_out GEMM
  for (int half = 0; half < 2; half++) {
    const int b0 = half * 2;
    dwg_t_kernel<<<dim3(64, 16, 2), 256, 0, stream>>>(hbuf, wdw, gt, b0);
    mfma_gemm<1><<<dim3(3, 128, 2), 256, 0, stream>>>(
        woutB, gt, xa + (size_t)b0 * HWC, out + (size_t)b0 * HWC,
        192, HW, 512, (size_t)HW * 512, HWC, HWC);
  }
}